// Round 11
// baseline (986.044 us; speedup 1.0000x reference)
//
#include <hip/hip_runtime.h>
#include <hip/hip_bf16.h>

typedef __hip_bfloat16 bf16;
typedef __attribute__((ext_vector_type(8))) short short8;
typedef __attribute__((ext_vector_type(4))) float f32x4;

#define NB 16
#define PLANE (256*256)

static __device__ __forceinline__ short f2bf(float v){
    __hip_bfloat16 h = __float2bfloat16(v);
    short s; __builtin_memcpy(&s, &h, 2); return s;
}
static __device__ __forceinline__ float bf2f(short s){
    union { unsigned u; float f; } cv;
    cv.u = ((unsigned)(unsigned short)s) << 16; return cv.f;
}

// agent-scope (cross-XCD coherent, uncached) accesses — bypass per-XCD L2
static __device__ __forceinline__ void  stg_ag(float* p, float v){
    __hip_atomic_store(p, v, __ATOMIC_RELAXED, __HIP_MEMORY_SCOPE_AGENT);
}
static __device__ __forceinline__ float ldg_ag(const float* p){
    return __hip_atomic_load(p, __ATOMIC_RELAXED, __HIP_MEMORY_SCOPE_AGENT);
}
// packed 16B coherent store/load: payload (3 floats) + seq flag land/observe atomically
static __device__ __forceinline__ void stg4_ag(float* p, f32x4 v){
    asm volatile("global_store_dwordx4 %0, %1, off sc0 sc1" :: "v"(p), "v"(v) : "memory");
}
static __device__ __forceinline__ f32x4 ldg4_ag(const float* p){
    f32x4 r;
    asm volatile("global_load_dwordx4 %0, %1, off sc0 sc1\n\ts_waitcnt vmcnt(0)"
                 : "=v"(r) : "v"(p) : "memory");
    return r;
}

// ---------------- first-layer conv 3x3 (small CIN, VALU), output channel-last bf16 ----------------
template<int CIN, int SPLIT, bool RELU>
__global__ __launch_bounds__(256)
void conv3x3_first(const float* __restrict__ in, const float* __restrict__ in2,
                   const float* __restrict__ wgt, const float* __restrict__ bias,
                   bf16* __restrict__ out)
{
    __shared__ float s_in[CIN][18][18];
    __shared__ float s_w[CIN*9*32];
    const int n  = blockIdx.z;
    const int ty0 = blockIdx.y * 16, tx0 = blockIdx.x * 16;
    const int tid = threadIdx.x;

    for (int idx = tid; idx < CIN*9*32; idx += 256) {
        int co = idx & 31; int rest = idx >> 5;     // rest = ci*9 + k
        s_w[idx] = wgt[(co*CIN + rest/9)*9 + rest%9];
    }
    for (int idx = tid; idx < CIN*18*18; idx += 256) {
        int ci = idx / (18*18); int rr = idx % (18*18);
        int yy = rr / 18, xx = rr % 18;
        int y = ty0 + yy - 1, x = tx0 + xx - 1;
        float v = 0.f;
        if (y >= 0 && y < 256 && x >= 0 && x < 256) {
            if (ci < SPLIT) v = in [((size_t)(n*SPLIT + ci)*256 + y)*256 + x];
            else            v = in2[((size_t)(n*(CIN-SPLIT) + (ci-SPLIT))*256 + y)*256 + x];
        }
        s_in[ci][yy][xx] = v;
    }
    __syncthreads();

    const int ty = tid >> 4, tx = tid & 15;
    float acc[32];
    #pragma unroll
    for (int co = 0; co < 32; co++) acc[co] = bias[co];

    #pragma unroll
    for (int ci = 0; ci < CIN; ci++) {
        #pragma unroll
        for (int ky = 0; ky < 3; ky++)
        #pragma unroll
        for (int kx = 0; kx < 3; kx++) {
            float v = s_in[ci][ty+ky][tx+kx];
            const float* wp = &s_w[(ci*9 + ky*3 + kx)*32];
            #pragma unroll
            for (int co = 0; co < 32; co++) acc[co] = fmaf(v, wp[co], acc[co]);
        }
    }
    const int y = ty0 + ty, x = tx0 + tx;
    size_t base = (((size_t)n*256 + y)*256 + x)*32;
    #pragma unroll
    for (int c = 0; c < 32; c += 8) {
        short8 vv;
        #pragma unroll
        for (int j = 0; j < 8; j++) {
            float v = acc[c+j];
            if (RELU) v = fmaxf(v, 0.f);
            vv[j] = f2bf(v);
        }
        *(short8*)((short*)out + base + c) = vv;
    }
}

// ---------------- weight repack for MFMA convs: [co][ci][tap] f32 -> [tap][co][ci] bf16 ----------------
__global__ __launch_bounds__(256)
void wrepack3(const float* __restrict__ a, const float* __restrict__ b,
              const float* __restrict__ c,
              bf16* __restrict__ oa, bf16* __restrict__ ob, bf16* __restrict__ oc)
{
    int j = blockIdx.x*256 + threadIdx.x;        // 0..27647
    if (j >= 3*9216) return;
    int set = j / 9216, r = j % 9216;
    int tap = r >> 10, rem = r & 1023, co = rem >> 5, ci = rem & 31;
    const float* src = (set == 0) ? a : (set == 1) ? b : c;
    bf16* dst = (set == 0) ? oa : (set == 1) ? ob : oc;
    dst[r] = __float2bfloat16(src[(co*32 + ci)*9 + tap]);
}

// ---------------- heavy conv 3x3 (32->32) via MFMA, LDS-staged input (v branch) ----------------
template<bool RELU>
__global__ __launch_bounds__(256)
void conv3x3_mfma(const bf16* __restrict__ in, const bf16* __restrict__ wpk,
                  const float* __restrict__ bias, bf16* __restrict__ out)
{
    __shared__ __align__(16) short s_a[4*2640];
    const int tid = threadIdx.x;
    const int lane = tid & 63, wid = tid >> 6;
    const int m = lane & 15, quad = lane >> 4, k0 = quad*8;
    const int n  = blockIdx.z;
    const int x0 = blockIdx.x * 16;
    const int y0 = blockIdx.y * 16;

    const short* inp = (const short*)in + (size_t)n*PLANE*32;
    short* outp = (short*)out + (size_t)n*PLANE*32;

    for (int c = tid; c < 1296; c += 256) {
        int q = c & 3, px = c >> 2;
        int yy = px / 18, xx = px - yy*18;
        int gy = y0 + yy - 1, gx = x0 + xx - 1;
        short8 v = {0,0,0,0,0,0,0,0};
        if ((unsigned)gy < 256u && (unsigned)gx < 256u)
            v = *(const short8*)(inp + ((size_t)(gy*256 + gx))*32 + q*8);
        *(short8*)(s_a + q*2640 + (yy*18 + xx)*8) = v;
    }

    const short* wp = (const short*)wpk;
    short8 bw[2][9];
    #pragma unroll
    for (int g = 0; g < 2; g++)
        #pragma unroll
        for (int tap = 0; tap < 9; tap++)
            bw[g][tap] = *(const short8*)(wp + ((tap*32 + g*16 + m)*32 + k0));
    const float b0 = bias[m], b1 = bias[16 + m];
    __syncthreads();

    const short* sa = s_a + quad*2640;
    #pragma unroll
    for (int r = 0; r < 4; r++) {
        const int lr = wid*4 + r;
        f32x4 acc0 = { b0, b0, b0, b0 };
        f32x4 acc1 = { b1, b1, b1, b1 };
        #pragma unroll
        for (int ky = 0; ky < 3; ky++)
        #pragma unroll
        for (int kx = 0; kx < 3; kx++) {
            short8 a = *(const short8*)(sa + ((lr+ky)*18 + (m+kx))*8);
            acc0 = __builtin_amdgcn_mfma_f32_16x16x32_bf16(a, bw[0][ky*3+kx], acc0, 0, 0, 0);
            acc1 = __builtin_amdgcn_mfma_f32_16x16x32_bf16(a, bw[1][ky*3+kx], acc1, 0, 0, 0);
        }
        const int y = y0 + lr;
        #pragma unroll
        for (int reg = 0; reg < 4; reg++) {
            int px = x0 + quad*4 + reg;
            size_t idx = ((size_t)y*256 + px)*32;
            float v0 = acc0[reg], v1 = acc1[reg];
            if (RELU) { v0 = fmaxf(v0, 0.f); v1 = fmaxf(v1, 0.f); }
            outp[idx + m]      = f2bf(v0);
            outp[idx + 16 + m] = f2bf(v1);
        }
    }
}

// ======== featfuse: conv2_g+dvdh_g, conv2_s+dvdh_s(sum), aff2 — all in one dispatch ========
// conv2 geometry (r9-verified): 18x18 tile (global [y0-1,y0+16]x[x0-1,x0+16]) from a
// 20x20 conv1 halo; extra cols lx=16,17 via D rows 0,1 of quad 0 (bit-identical to
// neighbor-block MFMA). dvdh over 17x17 in LDS (exact dvdh_cl order, g then s-sum).
// aff2 inline (r9-verified indices). Only wvh+aff touch HBM.
__global__ __launch_bounds__(256, 2)
void featfuse(const bf16* __restrict__ ing, const bf16* __restrict__ ins,
              const bf16* __restrict__ wpk1, const float* __restrict__ gb2,
              const bf16* __restrict__ wpk2, const float* __restrict__ sb2,
              const float* __restrict__ llam, const float* __restrict__ lmu,
              unsigned* __restrict__ wvh, float* __restrict__ aff)
{
    __shared__ __align__(16) short s_a[4*3248];     // 20x20 conv1 halo, 4 ch-slices
    __shared__ __align__(16) short s_f[18*18*40];   // conv2 out 18x18, 40-short px stride
    __shared__ float s_dv[17][17], s_dh[17][17];

    const int tid = threadIdx.x;
    const int lane = tid & 63, wid = tid >> 6;
    const int m = lane & 15, quad = lane >> 4, k0 = quad*8;
    const int n  = blockIdx.z;
    const int x0 = blockIdx.x * 16;
    const int y0 = blockIdx.y * 16;

    // stage 20x20 halo of a conv1 output (channel-last bf16 global), zero-padded
    auto stage20 = [&](const short* inp){
        for (int c = tid; c < 1600; c += 256) {
            int q = c & 3, px = c >> 2;
            int yy = px / 20, xx = px - yy*20;
            int gy = y0 + yy - 2, gx = x0 + xx - 2;
            short8 v = {0,0,0,0,0,0,0,0};
            if ((unsigned)gy < 256u && (unsigned)gx < 256u)
                v = *(const short8*)(inp + ((size_t)(gy*256 + gx))*32 + q*8);
            *(short8*)(s_a + q*3248 + (yy*20 + xx)*8) = v;
        }
    };

    // conv2 (r9-verified): 18 rows x (16 main + 2 extra) cols
    auto conv2 = [&](const bf16* wpk, const float* bias){
        const short* wp = (const short*)wpk;
        short8 bw[2][9];
        #pragma unroll
        for (int g = 0; g < 2; g++)
            #pragma unroll
            for (int tap = 0; tap < 9; tap++)
                bw[g][tap] = *(const short8*)(wp + ((tap*32 + g*16 + m)*32 + k0));
        const float b0 = bias[m], b1 = bias[16 + m];
        const short* sa = s_a + quad*3248;

        for (int ly = wid; ly < 18; ly += 4) {
            f32x4 acc0 = { b0, b0, b0, b0 };
            f32x4 acc1 = { b1, b1, b1, b1 };
            #pragma unroll
            for (int ky = 0; ky < 3; ky++)
            #pragma unroll
            for (int kx = 0; kx < 3; kx++) {
                short8 a = *(const short8*)(sa + ((ly+ky)*20 + (m+kx))*8);
                acc0 = __builtin_amdgcn_mfma_f32_16x16x32_bf16(a, bw[0][ky*3+kx], acc0, 0, 0, 0);
                acc1 = __builtin_amdgcn_mfma_f32_16x16x32_bf16(a, bw[1][ky*3+kx], acc1, 0, 0, 0);
            }
            #pragma unroll
            for (int reg = 0; reg < 4; reg++) {
                int lx = quad*4 + reg;
                short* fp = s_f + (ly*18 + lx)*40;
                fp[m]      = f2bf(acc0[reg]);
                fp[16 + m] = f2bf(acc1[reg]);
            }
            // extra cols lx=16,17 (A rows 0,1 valid; others clamped garbage, discarded)
            f32x4 e0 = { b0, b0, b0, b0 };
            f32x4 e1 = { b1, b1, b1, b1 };
            #pragma unroll
            for (int ky = 0; ky < 3; ky++)
            #pragma unroll
            for (int kx = 0; kx < 3; kx++) {
                int col = 16 + m + kx; if (col > 19) col = 19;
                short8 a = *(const short8*)(sa + ((ly+ky)*20 + col)*8);
                e0 = __builtin_amdgcn_mfma_f32_16x16x32_bf16(a, bw[0][ky*3+kx], e0, 0, 0, 0);
                e1 = __builtin_amdgcn_mfma_f32_16x16x32_bf16(a, bw[1][ky*3+kx], e1, 0, 0, 0);
            }
            if (quad == 0) {
                #pragma unroll
                for (int reg = 0; reg < 2; reg++) {
                    short* fp = s_f + (ly*18 + 16 + reg)*40;
                    fp[m]      = f2bf(e0[reg]);
                    fp[16 + m] = f2bf(e1[reg]);
                }
            }
        }
    };

    // dvdh over 17x17 (r9-verified, exact dvdh_cl FMA order)
    auto dvdh = [&](bool accum){
        for (int p = tid; p < 289; p += 256) {
            int li = p / 17, lj = p % 17;
            int gi = y0 - 1 + li, gj = x0 - 1 + lj;
            const short8* pc = (const short8*)(s_f + (li*18 + lj)*40);
            const short8* pr = (gj < 255) ? (const short8*)(s_f + (li*18 + lj + 1)*40) : pc;
            const short8* pd = (gi < 255) ? (const short8*)(s_f + ((li+1)*18 + lj)*40) : pc;
            float adv = 0.f, adh = 0.f;
            #pragma unroll
            for (int c4 = 0; c4 < 4; c4++) {
                short8 sc = pc[c4], sr = pr[c4], sd = pd[c4];
                #pragma unroll
                for (int e = 0; e < 8; e++) {
                    float fc = bf2f(sc[e]);
                    float d1 = bf2f(sr[e]) - fc;
                    float d2 = bf2f(sd[e]) - fc;
                    adh = fmaf(d1, d1, adh);
                    adv = fmaf(d2, d2, adv);
                }
            }
            if (accum) { s_dv[li][lj] += adv; s_dh[li][lj] += adh; }
            else       { s_dv[li][lj]  = adv; s_dh[li][lj]  = adh; }
        }
    };

    const short* ipg = (const short*)ing + (size_t)n*PLANE*32;
    const short* ips = (const short*)ins + (size_t)n*PLANE*32;

    stage20(ipg);
    __syncthreads();
    conv2(wpk1, gb2);
    __syncthreads();
    dvdh(false);
    stage20(ips);           // s_a free (conv2_g done); runs alongside dvdh_g
    __syncthreads();
    conv2(wpk2, sb2);
    __syncthreads();
    dvdh(true);
    __syncthreads();

    // aff2 inline for the 16x16 interior (r9-verified indices, exact aff2 math)
    const int ty = tid >> 4, tx = tid & 15;
    const int h = y0 + ty, w = x0 + tx;
    const float mu = expf(lmu[0]), lam = expf(llam[0]);
    int rb = (n*256 + h)*256 + w;
    float wvv = (h < 255) ? expf(-mu * s_dv[ty+1][tx+1]) : 0.f;
    float whv = (w < 255) ? expf(-mu * s_dh[ty+1][tx+1]) : 0.f;
    unsigned pv = (unsigned)(unsigned short)f2bf(wvv);
    unsigned ph = (unsigned)(unsigned short)f2bf(whv);
    wvh[rb] = pv | (ph << 16);
    float w_up = (h > 0) ? expf(-mu * s_dv[ty][tx+1]) : 0.f;
    float w_lf = (w > 0) ? expf(-mu * s_dh[ty+1][tx]) : 0.f;
    float ctr  = w_up + wvv + w_lf + whv + lam;
    float* a = aff + ((size_t)n*5)*PLANE + h*256 + w;
    a[0]        = w_up;
    a[PLANE]    = wvv;
    a[2*PLANE]  = w_lf;
    a[3*PLANE]  = whv;
    a[4*PLANE]  = ctr;
}

// ---------------- final conv 3x3 (32->1), channel-last input ----------------
__global__ __launch_bounds__(256)
void conv3x3_last(const bf16* __restrict__ in, const float* __restrict__ wgt,
                  const float* __restrict__ bias, float* __restrict__ out)
{
    __shared__ float s_w[288];
    int tid = threadIdx.x;
    for (int i = tid; i < 288; i += 256) s_w[i] = wgt[i];
    __syncthreads();
    int gid = blockIdx.x*256 + tid;
    int n = gid >> 16, h = (gid >> 8) & 255, w = gid & 255;
    const short* inp = (const short*)in + (size_t)n*PLANE*32;
    float sum = bias[0];
    #pragma unroll
    for (int ky = 0; ky < 3; ky++) {
        int yy = h + ky - 1;
        if ((unsigned)yy >= 256u) continue;
        #pragma unroll
        for (int kx = 0; kx < 3; kx++) {
            int xx = w + kx - 1;
            if ((unsigned)xx >= 256u) continue;
            const short8* pp = (const short8*)(inp + ((size_t)yy*256 + xx)*32);
            int tap = ky*3 + kx;
            #pragma unroll
            for (int c4 = 0; c4 < 4; c4++) {
                short8 v = pp[c4];
                #pragma unroll
                for (int j = 0; j < 8; j++)
                    sum = fmaf(bf2f(v[j]), s_w[(c4*8+j)*9 + tap], sum);
            }
        }
    }
    out[gid] = sum;
}

// ============ persistent CG: 512 workers, 2-level reduce, PACKED 16B sync lines ============
__global__ __launch_bounds__(256, 2)
void cg_persist(const unsigned* __restrict__ wvh, const float* __restrict__ mask,
                const float* __restrict__ src, const float* __restrict__ ybic,
                const float* __restrict__ llam, float* __restrict__ xout,
                float* __restrict__ ebuf0, float* __restrict__ ebuf1,
                float* __restrict__ part4, float* __restrict__ res4)
{
    __shared__ float s_pn[66][34];
    __shared__ float s_part[256], s_bs[32];
    __shared__ float s_w3[12];
    __shared__ __align__(16) float s_g[16];

    const int tid = threadIdx.x;
    const int wb = blockIdx.x;
    const int n = wb >> 5, t = wb & 31;
    const int tyo = (t >> 3) * 64, txo = (t & 7) * 32;
    const int tx = tid & 31, tyb = tid >> 5;
    const int w = txo + tx;
    const float lam = expf(llam[0]);
    const bool is_leader = ((wb & 127) == 0);

    const unsigned* wn = wvh + (size_t)n*PLANE;
    const float* ybn = ybic + (size_t)n*PLANE;

    int idx[8];
    unsigned wc[8], wu[8], wl[8];
    float c1[8], rhs[8];
    #pragma unroll
    for (int i = 0; i < 8; i++) {
        int hhi = tyo + tyb + 8*i;
        idx[i] = hhi*256 + w;
        wc[i] = wn[idx[i]];
        wu[i] = (hhi > 0) ? wn[idx[i]-256] : 0u;
        wl[i] = (w > 0)   ? wn[idx[i]-1]   : 0u;
        int bi = n*1024 + (hhi>>3)*32 + (w>>3);
        float mv = mask[bi];
        c1[i]  = lam*mv*(1.f/4096.f);
        rhs[i] = lam*mv*src[bi]*(1.f/64.f);
    }

    const bool hthr = (tid < 192);
    int hy = 0, hx = 0; bool hin = false; int nb = 0, eoff = 0;
    if (hthr) {
        if      (tid < 32)  { hy = tyo - 1;         hx = txo + tid;
                              nb = wb - 8; eoff = 32 + tid; }
        else if (tid < 64)  { hy = tyo + 64;        hx = txo + (tid-32);
                              nb = wb + 8; eoff = tid - 32; }
        else if (tid < 128) { hy = tyo + (tid-64);  hx = txo - 1;
                              nb = wb - 1; eoff = 128 + (tid-64); }
        else                { hy = tyo + (tid-128); hx = txo + 32;
                              nb = wb + 1; eoff = 64 + (tid-128); }
        hin = (hy >= 0 && hy < 256 && hx >= 0 && hx < 256);
    }
    const int hsy = hy - tyo + 1, hsx = hx - txo + 1;

    #define POOL_BLOCK() do { \
        __syncthreads(); \
        { int segrow_ = tid >> 2, segcol_ = tid & 3; \
          const float* rw_ = &s_pn[1 + segrow_][1 + segcol_*8]; \
          s_part[tid] = rw_[0]+rw_[1]+rw_[2]+rw_[3]+rw_[4]+rw_[5]+rw_[6]+rw_[7]; } \
        __syncthreads(); \
        if (tid < 32) { int brow_ = tid >> 2, bcol_ = tid & 3; float s_ = 0.f; \
          _Pragma("unroll") \
          for (int rr_ = 0; rr_ < 8; rr_++) s_ += s_part[(brow_*8 + rr_)*4 + bcol_]; \
          s_bs[tid] = s_; } \
        __syncthreads(); \
    } while (0)

    #define PUBLISH_E(arr, ebase) do { \
        float* eb_ = (ebase) + (size_t)wb*192; \
        if (tyb == 0) stg_ag(eb_ + tx, arr[0]); \
        if (tyb == 7) stg_ag(eb_ + 32 + tx, arr[7]); \
        if (tx == 0) { _Pragma("unroll") \
            for (int i_ = 0; i_ < 8; i_++) stg_ag(eb_ + 64 + tyb + 8*i_, arr[i_]); } \
        if (tx == 31){ _Pragma("unroll") \
            for (int i_ = 0; i_ < 8; i_++) stg_ag(eb_ + 128 + tyb + 8*i_, arr[i_]); } \
    } while (0)

    auto matvec = [&](int i) -> float {
        int yy = 1 + tyb + 8*i, xx = 1 + tx;
        float wvd = bf2f((short)(wc[i] & 0xffff));
        float whr = bf2f((short)(wc[i] >> 16));
        float wvu = bf2f((short)(wu[i] & 0xffff));
        float whl = bf2f((short)(wl[i] >> 16));
        float s = wvu*s_pn[yy-1][xx] + wvd*s_pn[yy+1][xx]
                + whl*s_pn[yy][xx-1] + whr*s_pn[yy][xx+1];
        float deg = wvu+wvd+whl+whr;
        return deg*s_pn[yy][xx] - s + c1[i]*s_bs[i*4 + (tx>>3)];
    };

    auto publish_red = [&](unsigned seq, float va, float vb, float vc){
        #pragma unroll
        for (int o = 32; o > 0; o >>= 1) {
            va += __shfl_down(va, o, 64);
            vb += __shfl_down(vb, o, 64);
            vc += __shfl_down(vc, o, 64);
        }
        asm volatile("s_waitcnt vmcnt(0)" ::: "memory");  // per-wave edge-store drain
        __syncthreads();
        if ((tid & 63) == 0) { int wv = tid >> 6; s_w3[wv*3]=va; s_w3[wv*3+1]=vb; s_w3[wv*3+2]=vc; }
        __syncthreads();
        if (tid == 0) {
            f32x4 pk;
            pk[0] = s_w3[0]+s_w3[3]+s_w3[6]+s_w3[9];
            pk[1] = s_w3[1]+s_w3[4]+s_w3[7]+s_w3[10];
            pk[2] = s_w3[2]+s_w3[5]+s_w3[8]+s_w3[11];
            pk[3] = __uint_as_float(seq);
            stg4_ag(part4 + (size_t)((seq & 1)*512 + wb)*4, pk);
        }
    };

    float o0, o1, o2;
    auto allred = [&](unsigned seq){
        float* resp = res4 + (size_t)(seq & 1)*64;
        if (is_leader && tid < 64) {
            const float* pl = part4 + (size_t)(seq & 1)*2048;
            const float* p0 = pl + (size_t)(wb + 2*tid)*4;
            f32x4 a0 = ldg4_ag(p0);
            while (__float_as_uint(a0[3]) < seq) { __builtin_amdgcn_s_sleep(1); a0 = ldg4_ag(p0); }
            f32x4 a1 = ldg4_ag(p0 + 4);
            while (__float_as_uint(a1[3]) < seq) { __builtin_amdgcn_s_sleep(1); a1 = ldg4_ag(p0 + 4); }
            float pa = a0[0] + a1[0];
            float pb = a0[1] + a1[1];
            float pc = a0[2] + a1[2];
            #pragma unroll
            for (int o = 32; o > 0; o >>= 1) {
                pa += __shfl_down(pa, o, 64);
                pb += __shfl_down(pb, o, 64);
                pc += __shfl_down(pc, o, 64);
            }
            if (tid == 0) {
                f32x4 rk; rk[0] = pa; rk[1] = pb; rk[2] = pc; rk[3] = __uint_as_float(seq);
                stg4_ag(resp + (wb >> 7)*16, rk);
            }
        }
        if (tid < 4) {
            const float* rl = resp + tid*16;
            f32x4 g = ldg4_ag(rl);
            while (__float_as_uint(g[3]) < seq) { __builtin_amdgcn_s_sleep(2); g = ldg4_ag(rl); }
            *(f32x4*)&s_g[tid*4] = g;
        }
        __syncthreads();
        o0 = ((s_g[0]+s_g[4])+s_g[8])+s_g[12];
        o1 = ((s_g[1]+s_g[5])+s_g[9])+s_g[13];
        o2 = ((s_g[2]+s_g[6])+s_g[10])+s_g[14];
    };

    float xv[8], rv[8], pv[8], apv[8];
    float rh = 0.f, phh = 0.f;

    // ---------- phase 1 (seq=1) ----------
    #pragma unroll
    for (int i = 0; i < 8; i++) {
        xv[i] = ybn[idx[i]];
        s_pn[1 + tyb + 8*i][1 + tx] = xv[i];
    }
    if (hthr) s_pn[hsy][hsx] = hin ? ybn[hy*256 + hx] : 0.f;
    POOL_BLOCK();
    float g0t = 0.f;
    #pragma unroll
    for (int i = 0; i < 8; i++) {
        float ax = matvec(i);
        float r0 = rhs[i] - ax;
        rv[i] = r0; pv[i] = r0;
        g0t += r0*r0;
    }
    PUBLISH_E(pv, ebuf1);
    publish_red(1u, 0.f, 0.f, 0.f);   // barrier-only phase
    allred(1u);

    // ---------- phase 2 (seq=2, k=0) ----------
    {
        float hv = 0.f;
        if (hthr && hin) hv = ldg_ag(ebuf1 + (size_t)nb*192 + eoff);
        if (hthr) { rh = hv; phh = hv; s_pn[hsy][hsx] = phh; }
        #pragma unroll
        for (int i = 0; i < 8; i++) s_pn[1 + tyb + 8*i][1 + tx] = pv[i];
        POOL_BLOCK();
        float pap = 0.f, apap = 0.f;
        #pragma unroll
        for (int i = 0; i < 8; i++) {
            float ap = matvec(i);
            apv[i] = ap;
            pap  += pv[i]*ap;
            apap += ap*ap;
        }
        PUBLISH_E(apv, ebuf0);
        publish_red(2u, g0t, pap, apap);
    }

    // ---------- main loop k=1..99 ----------
    for (int k = 1; k <= 99; k++) {
        float* ebR = ((k+1) & 1) ? ebuf1 : ebuf0;
        float* ebW = ((k+2) & 1) ? ebuf1 : ebuf0;

        allred((unsigned)(k + 1));
        float alpha = o0 / o1;
        float beta  = (alpha*alpha*o2 - o0) / o0;

        float hv = 0.f;
        if (hthr && hin) hv = ldg_ag(ebR + (size_t)nb*192 + eoff);

        float gsum = 0.f;
        #pragma unroll
        for (int i = 0; i < 8; i++) {
            float rN = fmaf(-alpha, apv[i], rv[i]);
            xv[i] = fmaf(alpha, pv[i], xv[i]);
            float pN = fmaf(beta, pv[i], rN);
            rv[i] = rN; pv[i] = pN;
            gsum += rN*rN;
            s_pn[1 + tyb + 8*i][1 + tx] = pN;
        }
        if (hthr) {
            rh  = fmaf(-alpha, hv, rh);
            phh = fmaf(beta, phh, rh);
            s_pn[hsy][hsx] = phh;
        }
        POOL_BLOCK();
        float pap = 0.f, apap = 0.f;
        #pragma unroll
        for (int i = 0; i < 8; i++) {
            float ap = matvec(i);
            apv[i] = ap;
            pap  += pv[i]*ap;
            apap += ap*ap;
        }
        PUBLISH_E(apv, ebW);
        publish_red((unsigned)(k + 2), gsum, pap, apap);
    }

    // ---------- tail ----------
    allred(101u);
    float alphaT = o0 / o1;
    float* xn = xout + (size_t)n*PLANE;
    #pragma unroll
    for (int i = 0; i < 8; i++) xn[idx[i]] = fmaf(alphaT, pv[i], xv[i]);

    #undef POOL_BLOCK
    #undef PUBLISH_E
}

// ---------------- host ----------------
extern "C" void kernel_launch(void* const* d_in, const int* in_sizes, int n_in,
                              void* d_out, int out_size, void* d_ws, size_t ws_size,
                              hipStream_t stream)
{
    (void)in_sizes; (void)n_in; (void)out_size; (void)ws_size;
    const float* guide = (const float*)d_in[0];
    const float* source= (const float*)d_in[1];
    const float* mask  = (const float*)d_in[2];
    const float* ybic  = (const float*)d_in[3];
    const float* gw1 = (const float*)d_in[4];  const float* gb1 = (const float*)d_in[5];
    const float* gw2 = (const float*)d_in[6];  const float* gb2 = (const float*)d_in[7];
    const float* sw1 = (const float*)d_in[8];  const float* sb1 = (const float*)d_in[9];
    const float* sw2 = (const float*)d_in[10]; const float* sb2 = (const float*)d_in[11];
    const float* vw1 = (const float*)d_in[12]; const float* vb1 = (const float*)d_in[13];
    const float* vw2 = (const float*)d_in[14]; const float* vb2 = (const float*)d_in[15];
    const float* vw3 = (const float*)d_in[16]; const float* vb3 = (const float*)d_in[17];
    const float* llam = (const float*)d_in[18];
    const float* lmu  = (const float*)d_in[19];

    float* out     = (float*)d_out;
    float* x_out   = out;                 // y_pred (16,1,256,256)
    float* var_out = out + 1048576;       // var
    float* aff_out = out + 2097152;       // aff (16,5,256,256)

    // ---- workspace layout ----
    char* ws = (char*)d_ws;
    float*    res4  = (float*)ws;                       // 2 parity x 4 x 16 floats [0,512)
    float*    part4 = (float*)(ws + 4096);              // 2 parity x 512 x 16B -> [4096, 20480)
    bf16*     wpk1  = (bf16*)(ws + 24576);              // 18 KiB each
    bf16*     wpk2  = (bf16*)(ws + 43008);
    bf16*     wpk3  = (bf16*)(ws + 61440);              // ends at 79872
    unsigned* wvh   = (unsigned*)(ws + 131072);         // [128 KiB, 128 KiB + 4 MiB)
    char*     A     = ws + 131072 + (size_t)NB*PLANE*4; // shared region
    // conv-phase mapping of A:
    bf16*  tmpA = (bf16*)(A);                                  // 64 MiB (conv1 g / v)
    bf16*  tmpB = (bf16*)(A + (size_t)NB*32*PLANE*2);          // 64 MiB (conv1 s / conv2 v)
    // CG-phase mapping of A (conv temporaries dead by then): compact edge buffers
    float* ebuf0 = (float*)A;                                  // 512*192 floats
    float* ebuf1 = (float*)(A + (size_t)512*192*4);

    dim3 cgrid(16, 16, NB);

    // zero res4 + part4 seq fields
    hipMemsetAsync(ws, 0, 20480, stream);

    // repack the three 32->32 conv weights into MFMA fragment layout
    wrepack3<<<108,256,0,stream>>>(gw2, sw2, vw2, wpk1, wpk2, wpk3);

    // feature branches: conv1_g -> tmpA, conv1_s -> tmpB, then one fused
    // conv2+dvdh+aff dispatch (no dv/dh/tmp2 round-trips)
    conv3x3_first<3,3,true><<<cgrid,256,0,stream>>>(guide, guide, gw1, gb1, tmpA);
    conv3x3_first<1,1,true><<<cgrid,256,0,stream>>>(ybic, ybic, sw1, sb1, tmpB);
    featfuse<<<cgrid,256,0,stream>>>(tmpA, tmpB, wpk1, gb2, wpk2, sb2,
                                     llam, lmu, wvh, aff_out);
    // variance branch (tmpA/tmpB reused after featfuse)
    conv3x3_first<4,3,true><<<cgrid,256,0,stream>>>(guide, ybic, vw1, vb1, tmpA);
    conv3x3_mfma<true><<<cgrid,256,0,stream>>>(tmpA, wpk3, vb2, tmpB);
    conv3x3_last<<<4096,256,0,stream>>>(tmpB, vw3, vb3, var_out);

    // CG: ONE persistent dispatch — 512 workers, packed-line 2-level barrier
    cg_persist<<<512,256,0,stream>>>(wvh, mask, source, ybic, llam, x_out,
                                     ebuf0, ebuf1, part4, res4);
}

// Round 12
// 876.016 us; speedup vs baseline: 1.1256x; 1.1256x over previous
//
#include <hip/hip_runtime.h>
#include <hip/hip_bf16.h>

typedef __hip_bfloat16 bf16;
typedef __attribute__((ext_vector_type(8))) short short8;
typedef __attribute__((ext_vector_type(4))) float f32x4;

#define NB 16
#define PLANE (256*256)

static __device__ __forceinline__ short f2bf(float v){
    __hip_bfloat16 h = __float2bfloat16(v);
    short s; __builtin_memcpy(&s, &h, 2); return s;
}
static __device__ __forceinline__ float bf2f(short s){
    union { unsigned u; float f; } cv;
    cv.u = ((unsigned)(unsigned short)s) << 16; return cv.f;
}

// agent-scope (cross-XCD coherent, uncached) accesses — bypass per-XCD L2
static __device__ __forceinline__ void  stg_ag(float* p, float v){
    __hip_atomic_store(p, v, __ATOMIC_RELAXED, __HIP_MEMORY_SCOPE_AGENT);
}
static __device__ __forceinline__ float ldg_ag(const float* p){
    return __hip_atomic_load(p, __ATOMIC_RELAXED, __HIP_MEMORY_SCOPE_AGENT);
}
// packed 16B coherent store/load: payload (3 floats) + seq flag land/observe atomically
static __device__ __forceinline__ void stg4_ag(float* p, f32x4 v){
    asm volatile("global_store_dwordx4 %0, %1, off sc0 sc1" :: "v"(p), "v"(v) : "memory");
}
static __device__ __forceinline__ f32x4 ldg4_ag(const float* p){
    f32x4 r;
    asm volatile("global_load_dwordx4 %0, %1, off sc0 sc1\n\ts_waitcnt vmcnt(0)"
                 : "=v"(r) : "v"(p) : "memory");
    return r;
}

// ---------------- conv1 body (exact conv3x3_first FMA order, RELU) ----------------
template<int CIN, int SPLIT>
static __device__ __forceinline__ void conv1_body(
    const float* __restrict__ in, const float* __restrict__ in2,
    const float* __restrict__ wgt, const float* __restrict__ bias,
    bf16* __restrict__ out, float* s_in, float* s_w,
    int n, int ty0, int tx0, int tid)
{
    for (int idx = tid; idx < CIN*9*32; idx += 256) {
        int co = idx & 31; int rest = idx >> 5;     // rest = ci*9 + k
        s_w[idx] = wgt[(co*CIN + rest/9)*9 + rest%9];
    }
    for (int idx = tid; idx < CIN*18*18; idx += 256) {
        int ci = idx / 324; int rr = idx % 324;
        int yy = rr / 18, xx = rr % 18;
        int y = ty0 + yy - 1, x = tx0 + xx - 1;
        float v = 0.f;
        if (y >= 0 && y < 256 && x >= 0 && x < 256) {
            if (ci < SPLIT) v = in [((size_t)(n*SPLIT + ci)*256 + y)*256 + x];
            else            v = in2[((size_t)(n*(CIN-SPLIT) + (ci-SPLIT))*256 + y)*256 + x];
        }
        s_in[ci*324 + yy*18 + xx] = v;
    }
    __syncthreads();

    const int ty = tid >> 4, tx = tid & 15;
    float acc[32];
    #pragma unroll
    for (int co = 0; co < 32; co++) acc[co] = bias[co];

    #pragma unroll
    for (int ci = 0; ci < CIN; ci++) {
        #pragma unroll
        for (int ky = 0; ky < 3; ky++)
        #pragma unroll
        for (int kx = 0; kx < 3; kx++) {
            float v = s_in[ci*324 + (ty+ky)*18 + (tx+kx)];
            const float* wp = &s_w[(ci*9 + ky*3 + kx)*32];
            #pragma unroll
            for (int co = 0; co < 32; co++) acc[co] = fmaf(v, wp[co], acc[co]);
        }
    }
    const int y = ty0 + ty, x = tx0 + tx;
    size_t base = (((size_t)n*256 + y)*256 + x)*32;
    #pragma unroll
    for (int c = 0; c < 32; c += 8) {
        short8 vv;
        #pragma unroll
        for (int j = 0; j < 8; j++)
            vv[j] = f2bf(fmaxf(acc[c+j], 0.f));
        *(short8*)((short*)out + base + c) = vv;
    }
}

// ---------------- conv1 for g and s branches in ONE dispatch (z 0..31) ----------------
__global__ __launch_bounds__(256)
void conv1_gs(const float* __restrict__ guide, const float* __restrict__ ybic,
              const float* __restrict__ gw1, const float* __restrict__ gb1,
              const float* __restrict__ sw1, const float* __restrict__ sb1,
              bf16* __restrict__ outg, bf16* __restrict__ outs)
{
    __shared__ float s_in[3*324];
    __shared__ float s_w[3*9*32];
    const int zz = blockIdx.z;
    const int br = zz >> 4, n = zz & 15;
    const int ty0 = blockIdx.y * 16, tx0 = blockIdx.x * 16;
    if (br == 0)
        conv1_body<3,3>(guide, guide, gw1, gb1, outg, s_in, s_w, n, ty0, tx0, threadIdx.x);
    else
        conv1_body<1,1>(ybic, ybic, sw1, sb1, outs, s_in, s_w, n, ty0, tx0, threadIdx.x);
}

// ---------------- weight repack for MFMA convs: [co][ci][tap] f32 -> [tap][co][ci] bf16 ----------------
__global__ __launch_bounds__(256)
void wrepack3(const float* __restrict__ a, const float* __restrict__ b,
              const float* __restrict__ c,
              bf16* __restrict__ oa, bf16* __restrict__ ob, bf16* __restrict__ oc)
{
    int j = blockIdx.x*256 + threadIdx.x;        // 0..27647
    if (j >= 3*9216) return;
    int set = j / 9216, r = j % 9216;
    int tap = r >> 10, rem = r & 1023, co = rem >> 5, ci = rem & 31;
    const float* src = (set == 0) ? a : (set == 1) ? b : c;
    bf16* dst = (set == 0) ? oa : (set == 1) ? ob : oc;
    dst[r] = __float2bfloat16(src[(co*32 + ci)*9 + tap]);
}

// ---------------- heavy conv 3x3 (32->32) via MFMA, LDS-staged input (v branch) ----------------
template<bool RELU>
__global__ __launch_bounds__(256)
void conv3x3_mfma(const bf16* __restrict__ in, const bf16* __restrict__ wpk,
                  const float* __restrict__ bias, bf16* __restrict__ out)
{
    __shared__ __align__(16) short s_a[4*2640];
    const int tid = threadIdx.x;
    const int lane = tid & 63, wid = tid >> 6;
    const int m = lane & 15, quad = lane >> 4, k0 = quad*8;
    const int n  = blockIdx.z;
    const int x0 = blockIdx.x * 16;
    const int y0 = blockIdx.y * 16;

    const short* inp = (const short*)in + (size_t)n*PLANE*32;
    short* outp = (short*)out + (size_t)n*PLANE*32;

    for (int c = tid; c < 1296; c += 256) {
        int q = c & 3, px = c >> 2;
        int yy = px / 18, xx = px - yy*18;
        int gy = y0 + yy - 1, gx = x0 + xx - 1;
        short8 v = {0,0,0,0,0,0,0,0};
        if ((unsigned)gy < 256u && (unsigned)gx < 256u)
            v = *(const short8*)(inp + ((size_t)(gy*256 + gx))*32 + q*8);
        *(short8*)(s_a + q*2640 + (yy*18 + xx)*8) = v;
    }

    const short* wp = (const short*)wpk;
    short8 bw[2][9];
    #pragma unroll
    for (int g = 0; g < 2; g++)
        #pragma unroll
        for (int tap = 0; tap < 9; tap++)
            bw[g][tap] = *(const short8*)(wp + ((tap*32 + g*16 + m)*32 + k0));
    const float b0 = bias[m], b1 = bias[16 + m];
    __syncthreads();

    const short* sa = s_a + quad*2640;
    #pragma unroll
    for (int r = 0; r < 4; r++) {
        const int lr = wid*4 + r;
        f32x4 acc0 = { b0, b0, b0, b0 };
        f32x4 acc1 = { b1, b1, b1, b1 };
        #pragma unroll
        for (int ky = 0; ky < 3; ky++)
        #pragma unroll
        for (int kx = 0; kx < 3; kx++) {
            short8 a = *(const short8*)(sa + ((lr+ky)*18 + (m+kx))*8);
            acc0 = __builtin_amdgcn_mfma_f32_16x16x32_bf16(a, bw[0][ky*3+kx], acc0, 0, 0, 0);
            acc1 = __builtin_amdgcn_mfma_f32_16x16x32_bf16(a, bw[1][ky*3+kx], acc1, 0, 0, 0);
        }
        const int y = y0 + lr;
        #pragma unroll
        for (int reg = 0; reg < 4; reg++) {
            int px = x0 + quad*4 + reg;
            size_t idx = ((size_t)y*256 + px)*32;
            float v0 = acc0[reg], v1 = acc1[reg];
            if (RELU) { v0 = fmaxf(v0, 0.f); v1 = fmaxf(v1, 0.f); }
            outp[idx + m]      = f2bf(v0);
            outp[idx + 16 + m] = f2bf(v1);
        }
    }
}

// ======== conv2+dvdh for BOTH feature branches in ONE dispatch (z 0..31) ========
// r8-verified conv3x3_mfma_dvdh body; the two branches run concurrently and
// accumulate into ZEROED dv/dh via atomicAdd. Bit-exact vs r8's write-then-add:
// dv = (0+adv_g)+adv_s or (0+adv_s)+adv_g — IEEE add commutes, +0 exact identity,
// both addends >= +0, so both orders give identical bits.
__global__ __launch_bounds__(256, 2)
void conv2gs_dvdh(const bf16* __restrict__ ing, const bf16* __restrict__ ins,
                  const bf16* __restrict__ wpk1, const float* __restrict__ gb2,
                  const bf16* __restrict__ wpk2, const float* __restrict__ sb2,
                  float* __restrict__ dv, float* __restrict__ dh)
{
    __shared__ __align__(16) short s_a[4*2896];     // conv1 19x19 halo tile, 4 ch-slices
    __shared__ __align__(16) short s_f[17*17*40];   // conv2 out 17x17, 40-short px stride
    const int tid = threadIdx.x;
    const int lane = tid & 63, wid = tid >> 6;
    const int m = lane & 15, quad = lane >> 4, k0 = quad*8;
    const int zz = blockIdx.z;
    const int br = zz >> 4, n = zz & 15;
    const int x0 = blockIdx.x * 16;
    const int y0 = blockIdx.y * 16;

    const bf16* in = br ? ins : ing;
    const bf16* wpk = br ? wpk2 : wpk1;
    const float* bias = br ? sb2 : gb2;

    const short* inp = (const short*)in + (size_t)n*PLANE*32;

    // stage 19x19 halo tile of conv1 output (global), zero-padded outside image
    for (int c = tid; c < 1444; c += 256) {
        int q = c & 3, px = c >> 2;
        int yy = px / 19, xx = px - yy*19;
        int gy = y0 + yy - 1, gx = x0 + xx - 1;
        short8 v = {0,0,0,0,0,0,0,0};
        if ((unsigned)gy < 256u && (unsigned)gx < 256u)
            v = *(const short8*)(inp + ((size_t)(gy*256 + gx))*32 + q*8);
        *(short8*)(s_a + q*2896 + (yy*19 + xx)*8) = v;
    }

    const short* wp = (const short*)wpk;
    short8 bw[2][9];
    #pragma unroll
    for (int g = 0; g < 2; g++)
        #pragma unroll
        for (int tap = 0; tap < 9; tap++)
            bw[g][tap] = *(const short8*)(wp + ((tap*32 + g*16 + m)*32 + k0));
    const float b0 = bias[m], b1 = bias[16 + m];
    __syncthreads();

    const short* sa = s_a + quad*2896;

    // main strips: wave wid covers local rows {wid, wid+4, wid+8, wid+12, (wid+16)}
    for (int ru = 0; ru < 5; ru++) {
        const int yl = wid + 4*ru;                  // 0..16
        if (yl > 16) break;
        f32x4 acc0 = { b0, b0, b0, b0 };
        f32x4 acc1 = { b1, b1, b1, b1 };
        #pragma unroll
        for (int ky = 0; ky < 3; ky++)
        #pragma unroll
        for (int kx = 0; kx < 3; kx++) {
            short8 a = *(const short8*)(sa + ((yl+ky)*19 + (kx+m))*8);
            acc0 = __builtin_amdgcn_mfma_f32_16x16x32_bf16(a, bw[0][ky*3+kx], acc0, 0, 0, 0);
            acc1 = __builtin_amdgcn_mfma_f32_16x16x32_bf16(a, bw[1][ky*3+kx], acc1, 0, 0, 0);
        }
        #pragma unroll
        for (int reg = 0; reg < 4; reg++) {
            int c = quad*4 + reg;
            short* fp = s_f + (yl*17 + c)*40;
            fp[m]      = f2bf(acc0[reg]);
            fp[16 + m] = f2bf(acc1[reg]);
        }
    }

    // extra-col strip: pixel col 16, rows 0..15 (A row 0 valid; rows>0 garbage, discarded)
    for (int ru = 0; ru < 4; ru++) {
        const int yl = wid + 4*ru;                  // 0..15
        f32x4 acc0 = { b0, b0, b0, b0 };
        f32x4 acc1 = { b1, b1, b1, b1 };
        #pragma unroll
        for (int ky = 0; ky < 3; ky++)
        #pragma unroll
        for (int kx = 0; kx < 3; kx++) {
            int col = 16 + kx + m; if (col > 18) col = 18;   // m>0 lanes: clamped garbage
            short8 a = *(const short8*)(sa + ((yl+ky)*19 + col)*8);
            acc0 = __builtin_amdgcn_mfma_f32_16x16x32_bf16(a, bw[0][ky*3+kx], acc0, 0, 0, 0);
            acc1 = __builtin_amdgcn_mfma_f32_16x16x32_bf16(a, bw[1][ky*3+kx], acc1, 0, 0, 0);
        }
        if (quad == 0) {                            // D row 0 lives in quad-0 lanes
            short* fp = s_f + (yl*17 + 16)*40;
            fp[m]      = f2bf(acc0[0]);
            fp[16 + m] = f2bf(acc1[0]);
        }
    }
    __syncthreads();

    // dv/dh for the 16x16 tile — exact dvdh_cl ordering, atomic accumulate
    const int ty = tid >> 4, tx = tid & 15;
    const int i = y0 + ty, j = x0 + tx;
    const short8* pc = (const short8*)(s_f + (ty*17 + tx)*40);
    const short8* pr = (j < 255) ? (const short8*)(s_f + (ty*17 + tx + 1)*40) : pc;
    const short8* pd = (i < 255) ? (const short8*)(s_f + ((ty+1)*17 + tx)*40) : pc;
    float adv = 0.f, adh = 0.f;
    #pragma unroll
    for (int c4 = 0; c4 < 4; c4++) {
        short8 sc = pc[c4], sr = pr[c4], sd = pd[c4];
        #pragma unroll
        for (int e = 0; e < 8; e++) {
            float fc = bf2f(sc[e]);
            float d1 = bf2f(sr[e]) - fc;
            float d2 = bf2f(sd[e]) - fc;
            adh = fmaf(d1, d1, adh);
            adv = fmaf(d2, d2, adv);
        }
    }
    int o = (n*256 + i)*256 + j;
    atomicAdd(&dv[o], adv);
    atomicAdd(&dh[o], adh);
}

// ---------------- final conv 3x3 (32->1), channel-last input ----------------
__global__ __launch_bounds__(256)
void conv3x3_last(const bf16* __restrict__ in, const float* __restrict__ wgt,
                  const float* __restrict__ bias, float* __restrict__ out)
{
    __shared__ float s_w[288];
    int tid = threadIdx.x;
    for (int i = tid; i < 288; i += 256) s_w[i] = wgt[i];
    __syncthreads();
    int gid = blockIdx.x*256 + tid;
    int n = gid >> 16, h = (gid >> 8) & 255, w = gid & 255;
    const short* inp = (const short*)in + (size_t)n*PLANE*32;
    float sum = bias[0];
    #pragma unroll
    for (int ky = 0; ky < 3; ky++) {
        int yy = h + ky - 1;
        if ((unsigned)yy >= 256u) continue;
        #pragma unroll
        for (int kx = 0; kx < 3; kx++) {
            int xx = w + kx - 1;
            if ((unsigned)xx >= 256u) continue;
            const short8* pp = (const short8*)(inp + ((size_t)yy*256 + xx)*32);
            int tap = ky*3 + kx;
            #pragma unroll
            for (int c4 = 0; c4 < 4; c4++) {
                short8 v = pp[c4];
                #pragma unroll
                for (int j = 0; j < 8; j++)
                    sum = fmaf(bf2f(v[j]), s_w[(c4*8+j)*9 + tap], sum);
            }
        }
    }
    out[gid] = sum;
}

// ======== conv1_v (blocks < 4096) + aff2 (blocks >= 4096) in ONE dispatch ========
__global__ __launch_bounds__(256)
void conv1v_aff(const float* __restrict__ guide, const float* __restrict__ ybic,
                const float* __restrict__ vw1, const float* __restrict__ vb1,
                bf16* __restrict__ outv,
                const float* __restrict__ dv, const float* __restrict__ dh,
                const float* __restrict__ llam, const float* __restrict__ lmu,
                unsigned* __restrict__ wvh, float* __restrict__ aff)
{
    __shared__ float s_in[4*324];
    __shared__ float s_w[4*9*32];
    const int b = blockIdx.x;
    if (b < 4096) {
        int n = b >> 8, by = (b >> 4) & 15, bx = b & 15;
        conv1_body<4,3>(guide, ybic, vw1, vb1, outv, s_in, s_w,
                        n, by*16, bx*16, threadIdx.x);
        return;
    }
    // aff2 body (exact r8 aff2_kernel math)
    int bid = b - 4096;
    int n = bid >> 8, h = bid & 255, w = threadIdx.x;
    float mu = expf(lmu[0]), lam = expf(llam[0]);
    int rb = (n*256 + h)*256 + w;
    float wvv = (h < 255) ? expf(-mu * dv[rb]) : 0.f;
    float whv = (w < 255) ? expf(-mu * dh[rb]) : 0.f;
    unsigned pv = (unsigned)(unsigned short)f2bf(wvv);
    unsigned ph = (unsigned)(unsigned short)f2bf(whv);
    wvh[rb] = pv | (ph << 16);
    float w_up = (h > 0) ? expf(-mu * dv[rb - 256]) : 0.f;
    float w_lf = (w > 0) ? expf(-mu * dh[rb - 1])   : 0.f;
    float ctr  = w_up + wvv + w_lf + whv + lam;
    float* a = aff + ((size_t)n*5)*PLANE + h*256 + w;
    a[0]        = w_up;
    a[PLANE]    = wvv;
    a[2*PLANE]  = w_lf;
    a[3*PLANE]  = whv;
    a[4*PLANE]  = ctr;
}

// ============ persistent CG: 512 workers, 2-level reduce, PACKED 16B sync lines ============
__global__ __launch_bounds__(256, 2)
void cg_persist(const unsigned* __restrict__ wvh, const float* __restrict__ mask,
                const float* __restrict__ src, const float* __restrict__ ybic,
                const float* __restrict__ llam, float* __restrict__ xout,
                float* __restrict__ ebuf0, float* __restrict__ ebuf1,
                float* __restrict__ part4, float* __restrict__ res4)
{
    __shared__ float s_pn[66][34];
    __shared__ float s_part[256], s_bs[32];
    __shared__ float s_w3[12];
    __shared__ __align__(16) float s_g[16];

    const int tid = threadIdx.x;
    const int wb = blockIdx.x;
    const int n = wb >> 5, t = wb & 31;
    const int tyo = (t >> 3) * 64, txo = (t & 7) * 32;
    const int tx = tid & 31, tyb = tid >> 5;
    const int w = txo + tx;
    const float lam = expf(llam[0]);
    const bool is_leader = ((wb & 127) == 0);

    const unsigned* wn = wvh + (size_t)n*PLANE;
    const float* ybn = ybic + (size_t)n*PLANE;

    int idx[8];
    unsigned wc[8], wu[8], wl[8];
    float c1[8], rhs[8];
    #pragma unroll
    for (int i = 0; i < 8; i++) {
        int hhi = tyo + tyb + 8*i;
        idx[i] = hhi*256 + w;
        wc[i] = wn[idx[i]];
        wu[i] = (hhi > 0) ? wn[idx[i]-256] : 0u;
        wl[i] = (w > 0)   ? wn[idx[i]-1]   : 0u;
        int bi = n*1024 + (hhi>>3)*32 + (w>>3);
        float mv = mask[bi];
        c1[i]  = lam*mv*(1.f/4096.f);
        rhs[i] = lam*mv*src[bi]*(1.f/64.f);
    }

    const bool hthr = (tid < 192);
    int hy = 0, hx = 0; bool hin = false; int nb = 0, eoff = 0;
    if (hthr) {
        if      (tid < 32)  { hy = tyo - 1;         hx = txo + tid;
                              nb = wb - 8; eoff = 32 + tid; }
        else if (tid < 64)  { hy = tyo + 64;        hx = txo + (tid-32);
                              nb = wb + 8; eoff = tid - 32; }
        else if (tid < 128) { hy = tyo + (tid-64);  hx = txo - 1;
                              nb = wb - 1; eoff = 128 + (tid-64); }
        else                { hy = tyo + (tid-128); hx = txo + 32;
                              nb = wb + 1; eoff = 64 + (tid-128); }
        hin = (hy >= 0 && hy < 256 && hx >= 0 && hx < 256);
    }
    const int hsy = hy - tyo + 1, hsx = hx - txo + 1;

    #define POOL_BLOCK() do { \
        __syncthreads(); \
        { int segrow_ = tid >> 2, segcol_ = tid & 3; \
          const float* rw_ = &s_pn[1 + segrow_][1 + segcol_*8]; \
          s_part[tid] = rw_[0]+rw_[1]+rw_[2]+rw_[3]+rw_[4]+rw_[5]+rw_[6]+rw_[7]; } \
        __syncthreads(); \
        if (tid < 32) { int brow_ = tid >> 2, bcol_ = tid & 3; float s_ = 0.f; \
          _Pragma("unroll") \
          for (int rr_ = 0; rr_ < 8; rr_++) s_ += s_part[(brow_*8 + rr_)*4 + bcol_]; \
          s_bs[tid] = s_; } \
        __syncthreads(); \
    } while (0)

    #define PUBLISH_E(arr, ebase) do { \
        float* eb_ = (ebase) + (size_t)wb*192; \
        if (tyb == 0) stg_ag(eb_ + tx, arr[0]); \
        if (tyb == 7) stg_ag(eb_ + 32 + tx, arr[7]); \
        if (tx == 0) { _Pragma("unroll") \
            for (int i_ = 0; i_ < 8; i_++) stg_ag(eb_ + 64 + tyb + 8*i_, arr[i_]); } \
        if (tx == 31){ _Pragma("unroll") \
            for (int i_ = 0; i_ < 8; i_++) stg_ag(eb_ + 128 + tyb + 8*i_, arr[i_]); } \
    } while (0)

    auto matvec = [&](int i) -> float {
        int yy = 1 + tyb + 8*i, xx = 1 + tx;
        float wvd = bf2f((short)(wc[i] & 0xffff));
        float whr = bf2f((short)(wc[i] >> 16));
        float wvu = bf2f((short)(wu[i] & 0xffff));
        float whl = bf2f((short)(wl[i] >> 16));
        float s = wvu*s_pn[yy-1][xx] + wvd*s_pn[yy+1][xx]
                + whl*s_pn[yy][xx-1] + whr*s_pn[yy][xx+1];
        float deg = wvu+wvd+whl+whr;
        return deg*s_pn[yy][xx] - s + c1[i]*s_bs[i*4 + (tx>>3)];
    };

    auto publish_red = [&](unsigned seq, float va, float vb, float vc){
        #pragma unroll
        for (int o = 32; o > 0; o >>= 1) {
            va += __shfl_down(va, o, 64);
            vb += __shfl_down(vb, o, 64);
            vc += __shfl_down(vc, o, 64);
        }
        asm volatile("s_waitcnt vmcnt(0)" ::: "memory");  // per-wave edge-store drain
        __syncthreads();
        if ((tid & 63) == 0) { int wv = tid >> 6; s_w3[wv*3]=va; s_w3[wv*3+1]=vb; s_w3[wv*3+2]=vc; }
        __syncthreads();
        if (tid == 0) {
            f32x4 pk;
            pk[0] = s_w3[0]+s_w3[3]+s_w3[6]+s_w3[9];
            pk[1] = s_w3[1]+s_w3[4]+s_w3[7]+s_w3[10];
            pk[2] = s_w3[2]+s_w3[5]+s_w3[8]+s_w3[11];
            pk[3] = __uint_as_float(seq);
            stg4_ag(part4 + (size_t)((seq & 1)*512 + wb)*4, pk);
        }
    };

    float o0, o1, o2;
    auto allred = [&](unsigned seq){
        float* resp = res4 + (size_t)(seq & 1)*64;
        if (is_leader && tid < 64) {
            const float* pl = part4 + (size_t)(seq & 1)*2048;
            const float* p0 = pl + (size_t)(wb + 2*tid)*4;
            f32x4 a0 = ldg4_ag(p0);
            while (__float_as_uint(a0[3]) < seq) { __builtin_amdgcn_s_sleep(1); a0 = ldg4_ag(p0); }
            f32x4 a1 = ldg4_ag(p0 + 4);
            while (__float_as_uint(a1[3]) < seq) { __builtin_amdgcn_s_sleep(1); a1 = ldg4_ag(p0 + 4); }
            float pa = a0[0] + a1[0];
            float pb = a0[1] + a1[1];
            float pc = a0[2] + a1[2];
            #pragma unroll
            for (int o = 32; o > 0; o >>= 1) {
                pa += __shfl_down(pa, o, 64);
                pb += __shfl_down(pb, o, 64);
                pc += __shfl_down(pc, o, 64);
            }
            if (tid == 0) {
                f32x4 rk; rk[0] = pa; rk[1] = pb; rk[2] = pc; rk[3] = __uint_as_float(seq);
                stg4_ag(resp + (wb >> 7)*16, rk);
            }
        }
        if (tid < 4) {
            const float* rl = resp + tid*16;
            f32x4 g = ldg4_ag(rl);
            while (__float_as_uint(g[3]) < seq) { __builtin_amdgcn_s_sleep(2); g = ldg4_ag(rl); }
            *(f32x4*)&s_g[tid*4] = g;
        }
        __syncthreads();
        o0 = ((s_g[0]+s_g[4])+s_g[8])+s_g[12];
        o1 = ((s_g[1]+s_g[5])+s_g[9])+s_g[13];
        o2 = ((s_g[2]+s_g[6])+s_g[10])+s_g[14];
    };

    float xv[8], rv[8], pv[8], apv[8];
    float rh = 0.f, phh = 0.f;

    // ---------- phase 1 (seq=1) ----------
    #pragma unroll
    for (int i = 0; i < 8; i++) {
        xv[i] = ybn[idx[i]];
        s_pn[1 + tyb + 8*i][1 + tx] = xv[i];
    }
    if (hthr) s_pn[hsy][hsx] = hin ? ybn[hy*256 + hx] : 0.f;
    POOL_BLOCK();
    float g0t = 0.f;
    #pragma unroll
    for (int i = 0; i < 8; i++) {
        float ax = matvec(i);
        float r0 = rhs[i] - ax;
        rv[i] = r0; pv[i] = r0;
        g0t += r0*r0;
    }
    PUBLISH_E(pv, ebuf1);
    publish_red(1u, 0.f, 0.f, 0.f);   // barrier-only phase
    allred(1u);

    // ---------- phase 2 (seq=2, k=0) ----------
    {
        float hv = 0.f;
        if (hthr && hin) hv = ldg_ag(ebuf1 + (size_t)nb*192 + eoff);
        if (hthr) { rh = hv; phh = hv; s_pn[hsy][hsx] = phh; }
        #pragma unroll
        for (int i = 0; i < 8; i++) s_pn[1 + tyb + 8*i][1 + tx] = pv[i];
        POOL_BLOCK();
        float pap = 0.f, apap = 0.f;
        #pragma unroll
        for (int i = 0; i < 8; i++) {
            float ap = matvec(i);
            apv[i] = ap;
            pap  += pv[i]*ap;
            apap += ap*ap;
        }
        PUBLISH_E(apv, ebuf0);
        publish_red(2u, g0t, pap, apap);
    }

    // ---------- main loop k=1..99 ----------
    for (int k = 1; k <= 99; k++) {
        float* ebR = ((k+1) & 1) ? ebuf1 : ebuf0;
        float* ebW = ((k+2) & 1) ? ebuf1 : ebuf0;

        allred((unsigned)(k + 1));
        float alpha = o0 / o1;
        float beta  = (alpha*alpha*o2 - o0) / o0;

        float hv = 0.f;
        if (hthr && hin) hv = ldg_ag(ebR + (size_t)nb*192 + eoff);

        float gsum = 0.f;
        #pragma unroll
        for (int i = 0; i < 8; i++) {
            float rN = fmaf(-alpha, apv[i], rv[i]);
            xv[i] = fmaf(alpha, pv[i], xv[i]);
            float pN = fmaf(beta, pv[i], rN);
            rv[i] = rN; pv[i] = pN;
            gsum += rN*rN;
            s_pn[1 + tyb + 8*i][1 + tx] = pN;
        }
        if (hthr) {
            rh  = fmaf(-alpha, hv, rh);
            phh = fmaf(beta, phh, rh);
            s_pn[hsy][hsx] = phh;
        }
        POOL_BLOCK();
        float pap = 0.f, apap = 0.f;
        #pragma unroll
        for (int i = 0; i < 8; i++) {
            float ap = matvec(i);
            apv[i] = ap;
            pap  += pv[i]*ap;
            apap += ap*ap;
        }
        PUBLISH_E(apv, ebW);
        publish_red((unsigned)(k + 2), gsum, pap, apap);
    }

    // ---------- tail ----------
    allred(101u);
    float alphaT = o0 / o1;
    float* xn = xout + (size_t)n*PLANE;
    #pragma unroll
    for (int i = 0; i < 8; i++) xn[idx[i]] = fmaf(alphaT, pv[i], xv[i]);

    #undef POOL_BLOCK
    #undef PUBLISH_E
}

// ---------------- host ----------------
extern "C" void kernel_launch(void* const* d_in, const int* in_sizes, int n_in,
                              void* d_out, int out_size, void* d_ws, size_t ws_size,
                              hipStream_t stream)
{
    (void)in_sizes; (void)n_in; (void)out_size; (void)ws_size;
    const float* guide = (const float*)d_in[0];
    const float* source= (const float*)d_in[1];
    const float* mask  = (const float*)d_in[2];
    const float* ybic  = (const float*)d_in[3];
    const float* gw1 = (const float*)d_in[4];  const float* gb1 = (const float*)d_in[5];
    const float* gw2 = (const float*)d_in[6];  const float* gb2 = (const float*)d_in[7];
    const float* sw1 = (const float*)d_in[8];  const float* sb1 = (const float*)d_in[9];
    const float* sw2 = (const float*)d_in[10]; const float* sb2 = (const float*)d_in[11];
    const float* vw1 = (const float*)d_in[12]; const float* vb1 = (const float*)d_in[13];
    const float* vw2 = (const float*)d_in[14]; const float* vb2 = (const float*)d_in[15];
    const float* vw3 = (const float*)d_in[16]; const float* vb3 = (const float*)d_in[17];
    const float* llam = (const float*)d_in[18];
    const float* lmu  = (const float*)d_in[19];

    float* out     = (float*)d_out;
    float* x_out   = out;                 // y_pred (16,1,256,256)
    float* var_out = out + 1048576;       // var
    float* aff_out = out + 2097152;       // aff (16,5,256,256)

    // ---- workspace layout ----
    char* ws = (char*)d_ws;
    float*    res4  = (float*)ws;                       // 2 parity x 4 x 16 floats [0,512)
    float*    part4 = (float*)(ws + 4096);              // 2 parity x 512 x 16B -> [4096, 20480)
    bf16*     wpk1  = (bf16*)(ws + 24576);              // 18 KiB each
    bf16*     wpk2  = (bf16*)(ws + 43008);
    bf16*     wpk3  = (bf16*)(ws + 61440);              // ends at 79872
    unsigned* wvh   = (unsigned*)(ws + 131072);         // [128 KiB, 128 KiB + 4 MiB)
    char*     A     = ws + 131072 + (size_t)NB*PLANE*4; // shared region (136 MiB)
    // conv-phase mapping of A:
    bf16*  tmpA = (bf16*)(A);                                  // 64 MiB (conv1 g / conv1 v)
    bf16*  tmpB = (bf16*)(A + (size_t)NB*32*PLANE*2);          // 64 MiB (conv1 s / conv2 v)
    float* dv   = (float*)(A + (size_t)NB*32*PLANE*4);         // 4 MiB
    float* dh   = (float*)(A + (size_t)NB*32*PLANE*4 + (size_t)NB*PLANE*4);
    // CG-phase mapping of A (conv temporaries dead by then): compact edge buffers
    float* ebuf0 = (float*)A;                                  // 512*192 floats
    float* ebuf1 = (float*)(A + (size_t)512*192*4);

    // zero res4 + part4 seq fields; zero dv/dh (atomic accumulation base)
    hipMemsetAsync(ws, 0, 20480, stream);
    hipMemsetAsync(dv, 0, (size_t)2*NB*PLANE*4, stream);

    // repack the three 32->32 conv weights into MFMA fragment layout
    wrepack3<<<108,256,0,stream>>>(gw2, sw2, vw2, wpk1, wpk2, wpk3);

    // conv1 for g and s branches concurrently (z 0..31)
    conv1_gs<<<dim3(16,16,2*NB),256,0,stream>>>(guide, ybic, gw1, gb1, sw1, sb1,
                                                tmpA, tmpB);
    // conv2+dvdh for both branches concurrently (atomicAdd into zeroed dv/dh)
    conv2gs_dvdh<<<dim3(16,16,2*NB),256,0,stream>>>(tmpA, tmpB, wpk1, gb2, wpk2, sb2,
                                                    dv, dh);
    // conv1_v (tmpA reuse) and aff2 concurrently in one dispatch
    conv1v_aff<<<8192,256,0,stream>>>(guide, ybic, vw1, vb1, tmpA,
                                      dv, dh, llam, lmu, wvh, aff_out);
    // variance branch tail
    conv3x3_mfma<true><<<dim3(16,16,NB),256,0,stream>>>(tmpA, wpk3, vb2, tmpB);
    conv3x3_last<<<4096,256,0,stream>>>(tmpB, vw3, vb3, var_out);

    // CG: ONE persistent dispatch — 512 workers, packed-line 2-level barrier
    cg_persist<<<512,256,0,stream>>>(wvh, mask, source, ybic, llam, x_out,
                                     ebuf0, ebuf1, part4, res4);
}

// Round 13
// 868.192 us; speedup vs baseline: 1.1357x; 1.0090x over previous
//
#include <hip/hip_runtime.h>
#include <hip/hip_bf16.h>

typedef __hip_bfloat16 bf16;
typedef __attribute__((ext_vector_type(8))) short short8;
typedef __attribute__((ext_vector_type(4))) float f32x4;

#define NB 16
#define PLANE (256*256)

static __device__ __forceinline__ short f2bf(float v){
    __hip_bfloat16 h = __float2bfloat16(v);
    short s; __builtin_memcpy(&s, &h, 2); return s;
}
static __device__ __forceinline__ float bf2f(short s){
    union { unsigned u; float f; } cv;
    cv.u = ((unsigned)(unsigned short)s) << 16; return cv.f;
}

// agent-scope (cross-XCD coherent, uncached) accesses — bypass per-XCD L2
static __device__ __forceinline__ void  stg_ag(float* p, float v){
    __hip_atomic_store(p, v, __ATOMIC_RELAXED, __HIP_MEMORY_SCOPE_AGENT);
}
static __device__ __forceinline__ float ldg_ag(const float* p){
    return __hip_atomic_load(p, __ATOMIC_RELAXED, __HIP_MEMORY_SCOPE_AGENT);
}
// packed 16B coherent store/load: payload (3 floats) + seq flag land/observe atomically
static __device__ __forceinline__ void stg4_ag(float* p, f32x4 v){
    asm volatile("global_store_dwordx4 %0, %1, off sc0 sc1" :: "v"(p), "v"(v) : "memory");
}
static __device__ __forceinline__ f32x4 ldg4_ag(const float* p){
    f32x4 r;
    asm volatile("global_load_dwordx4 %0, %1, off sc0 sc1\n\ts_waitcnt vmcnt(0)"
                 : "=v"(r) : "v"(p) : "memory");
    return r;
}

// ---------------- conv1 body (exact conv3x3_first FMA order, RELU) ----------------
template<int CIN, int SPLIT>
static __device__ __forceinline__ void conv1_body(
    const float* __restrict__ in, const float* __restrict__ in2,
    const float* __restrict__ wgt, const float* __restrict__ bias,
    bf16* __restrict__ out, float* s_in, float* s_w,
    int n, int ty0, int tx0, int tid)
{
    for (int idx = tid; idx < CIN*9*32; idx += 256) {
        int co = idx & 31; int rest = idx >> 5;     // rest = ci*9 + k
        s_w[idx] = wgt[(co*CIN + rest/9)*9 + rest%9];
    }
    for (int idx = tid; idx < CIN*18*18; idx += 256) {
        int ci = idx / 324; int rr = idx % 324;
        int yy = rr / 18, xx = rr % 18;
        int y = ty0 + yy - 1, x = tx0 + xx - 1;
        float v = 0.f;
        if (y >= 0 && y < 256 && x >= 0 && x < 256) {
            if (ci < SPLIT) v = in [((size_t)(n*SPLIT + ci)*256 + y)*256 + x];
            else            v = in2[((size_t)(n*(CIN-SPLIT) + (ci-SPLIT))*256 + y)*256 + x];
        }
        s_in[ci*324 + yy*18 + xx] = v;
    }
    __syncthreads();

    const int ty = tid >> 4, tx = tid & 15;
    float acc[32];
    #pragma unroll
    for (int co = 0; co < 32; co++) acc[co] = bias[co];

    #pragma unroll
    for (int ci = 0; ci < CIN; ci++) {
        #pragma unroll
        for (int ky = 0; ky < 3; ky++)
        #pragma unroll
        for (int kx = 0; kx < 3; kx++) {
            float v = s_in[ci*324 + (ty+ky)*18 + (tx+kx)];
            const float* wp = &s_w[(ci*9 + ky*3 + kx)*32];
            #pragma unroll
            for (int co = 0; co < 32; co++) acc[co] = fmaf(v, wp[co], acc[co]);
        }
    }
    const int y = ty0 + ty, x = tx0 + tx;
    size_t base = (((size_t)n*256 + y)*256 + x)*32;
    #pragma unroll
    for (int c = 0; c < 32; c += 8) {
        short8 vv;
        #pragma unroll
        for (int j = 0; j < 8; j++)
            vv[j] = f2bf(fmaxf(acc[c+j], 0.f));
        *(short8*)((short*)out + base + c) = vv;
    }
}

// ---------------- conv1 for g and s branches in ONE dispatch (z 0..31) ----------------
__global__ __launch_bounds__(256)
void conv1_gs(const float* __restrict__ guide, const float* __restrict__ ybic,
              const float* __restrict__ gw1, const float* __restrict__ gb1,
              const float* __restrict__ sw1, const float* __restrict__ sb1,
              bf16* __restrict__ outg, bf16* __restrict__ outs)
{
    __shared__ float s_in[3*324];
    __shared__ float s_w[3*9*32];
    const int zz = blockIdx.z;
    const int br = zz >> 4, n = zz & 15;
    const int ty0 = blockIdx.y * 16, tx0 = blockIdx.x * 16;
    if (br == 0)
        conv1_body<3,3>(guide, guide, gw1, gb1, outg, s_in, s_w, n, ty0, tx0, threadIdx.x);
    else
        conv1_body<1,1>(ybic, ybic, sw1, sb1, outs, s_in, s_w, n, ty0, tx0, threadIdx.x);
}

// ---------------- weight repack for MFMA convs: [co][ci][tap] f32 -> [tap][co][ci] bf16 ----------------
__global__ __launch_bounds__(256)
void wrepack3(const float* __restrict__ a, const float* __restrict__ b,
              const float* __restrict__ c,
              bf16* __restrict__ oa, bf16* __restrict__ ob, bf16* __restrict__ oc)
{
    int j = blockIdx.x*256 + threadIdx.x;        // 0..27647
    if (j >= 3*9216) return;
    int set = j / 9216, r = j % 9216;
    int tap = r >> 10, rem = r & 1023, co = rem >> 5, ci = rem & 31;
    const float* src = (set == 0) ? a : (set == 1) ? b : c;
    bf16* dst = (set == 0) ? oa : (set == 1) ? ob : oc;
    dst[r] = __float2bfloat16(src[(co*32 + ci)*9 + tap]);
}

// ======== conv2+dvdh for BOTH feature branches in ONE dispatch (z 0..31) ========
// r8-verified conv3x3_mfma_dvdh body; the two branches run concurrently and
// accumulate into ZEROED dv/dh via atomicAdd (bit-exact: IEEE add commutes,
// +0 exact identity, both addends >= +0).
__global__ __launch_bounds__(256, 2)
void conv2gs_dvdh(const bf16* __restrict__ ing, const bf16* __restrict__ ins,
                  const bf16* __restrict__ wpk1, const float* __restrict__ gb2,
                  const bf16* __restrict__ wpk2, const float* __restrict__ sb2,
                  float* __restrict__ dv, float* __restrict__ dh)
{
    __shared__ __align__(16) short s_a[4*2896];     // conv1 19x19 halo tile, 4 ch-slices
    __shared__ __align__(16) short s_f[17*17*40];   // conv2 out 17x17, 40-short px stride
    const int tid = threadIdx.x;
    const int lane = tid & 63, wid = tid >> 6;
    const int m = lane & 15, quad = lane >> 4, k0 = quad*8;
    const int zz = blockIdx.z;
    const int br = zz >> 4, n = zz & 15;
    const int x0 = blockIdx.x * 16;
    const int y0 = blockIdx.y * 16;

    const bf16* in = br ? ins : ing;
    const bf16* wpk = br ? wpk2 : wpk1;
    const float* bias = br ? sb2 : gb2;

    const short* inp = (const short*)in + (size_t)n*PLANE*32;

    // stage 19x19 halo tile of conv1 output (global), zero-padded outside image
    for (int c = tid; c < 1444; c += 256) {
        int q = c & 3, px = c >> 2;
        int yy = px / 19, xx = px - yy*19;
        int gy = y0 + yy - 1, gx = x0 + xx - 1;
        short8 v = {0,0,0,0,0,0,0,0};
        if ((unsigned)gy < 256u && (unsigned)gx < 256u)
            v = *(const short8*)(inp + ((size_t)(gy*256 + gx))*32 + q*8);
        *(short8*)(s_a + q*2896 + (yy*19 + xx)*8) = v;
    }

    const short* wp = (const short*)wpk;
    short8 bw[2][9];
    #pragma unroll
    for (int g = 0; g < 2; g++)
        #pragma unroll
        for (int tap = 0; tap < 9; tap++)
            bw[g][tap] = *(const short8*)(wp + ((tap*32 + g*16 + m)*32 + k0));
    const float b0 = bias[m], b1 = bias[16 + m];
    __syncthreads();

    const short* sa = s_a + quad*2896;

    // main strips: wave wid covers local rows {wid, wid+4, wid+8, wid+12, (wid+16)}
    for (int ru = 0; ru < 5; ru++) {
        const int yl = wid + 4*ru;                  // 0..16
        if (yl > 16) break;
        f32x4 acc0 = { b0, b0, b0, b0 };
        f32x4 acc1 = { b1, b1, b1, b1 };
        #pragma unroll
        for (int ky = 0; ky < 3; ky++)
        #pragma unroll
        for (int kx = 0; kx < 3; kx++) {
            short8 a = *(const short8*)(sa + ((yl+ky)*19 + (kx+m))*8);
            acc0 = __builtin_amdgcn_mfma_f32_16x16x32_bf16(a, bw[0][ky*3+kx], acc0, 0, 0, 0);
            acc1 = __builtin_amdgcn_mfma_f32_16x16x32_bf16(a, bw[1][ky*3+kx], acc1, 0, 0, 0);
        }
        #pragma unroll
        for (int reg = 0; reg < 4; reg++) {
            int c = quad*4 + reg;
            short* fp = s_f + (yl*17 + c)*40;
            fp[m]      = f2bf(acc0[reg]);
            fp[16 + m] = f2bf(acc1[reg]);
        }
    }

    // extra-col strip: pixel col 16, rows 0..15 (A row 0 valid; rows>0 garbage, discarded)
    for (int ru = 0; ru < 4; ru++) {
        const int yl = wid + 4*ru;                  // 0..15
        f32x4 acc0 = { b0, b0, b0, b0 };
        f32x4 acc1 = { b1, b1, b1, b1 };
        #pragma unroll
        for (int ky = 0; ky < 3; ky++)
        #pragma unroll
        for (int kx = 0; kx < 3; kx++) {
            int col = 16 + kx + m; if (col > 18) col = 18;   // m>0 lanes: clamped garbage
            short8 a = *(const short8*)(sa + ((yl+ky)*19 + col)*8);
            acc0 = __builtin_amdgcn_mfma_f32_16x16x32_bf16(a, bw[0][ky*3+kx], acc0, 0, 0, 0);
            acc1 = __builtin_amdgcn_mfma_f32_16x16x32_bf16(a, bw[1][ky*3+kx], acc1, 0, 0, 0);
        }
        if (quad == 0) {                            // D row 0 lives in quad-0 lanes
            short* fp = s_f + (yl*17 + 16)*40;
            fp[m]      = f2bf(acc0[0]);
            fp[16 + m] = f2bf(acc1[0]);
        }
    }
    __syncthreads();

    // dv/dh for the 16x16 tile — exact dvdh_cl ordering, atomic accumulate
    const int ty = tid >> 4, tx = tid & 15;
    const int i = y0 + ty, j = x0 + tx;
    const short8* pc = (const short8*)(s_f + (ty*17 + tx)*40);
    const short8* pr = (j < 255) ? (const short8*)(s_f + (ty*17 + tx + 1)*40) : pc;
    const short8* pd = (i < 255) ? (const short8*)(s_f + ((ty+1)*17 + tx)*40) : pc;
    float adv = 0.f, adh = 0.f;
    #pragma unroll
    for (int c4 = 0; c4 < 4; c4++) {
        short8 sc = pc[c4], sr = pr[c4], sd = pd[c4];
        #pragma unroll
        for (int e = 0; e < 8; e++) {
            float fc = bf2f(sc[e]);
            float d1 = bf2f(sr[e]) - fc;
            float d2 = bf2f(sd[e]) - fc;
            adh = fmaf(d1, d1, adh);
            adv = fmaf(d2, d2, adv);
        }
    }
    int o = (n*256 + i)*256 + j;
    atomicAdd(&dv[o], adv);
    atomicAdd(&dh[o], adh);
}

// ======== fused v-tail: conv2_v(MFMA, RELU) 18x18 in LDS -> conv3 (32->1) -> var ========
// conv2 geometry identical to conv2gs_dvdh / r11 featfuse (verified bit-exact);
// conv3 reads the 18x18 LDS tile with conv3x3_last's exact tap/FMA order.
// Removes the tmpB round-trip (64 MB write + 72 MB read) and one dispatch.
__global__ __launch_bounds__(256, 2)
void conv2v_last(const bf16* __restrict__ in, const bf16* __restrict__ wpk,
                 const float* __restrict__ bias,
                 const float* __restrict__ vw3, const float* __restrict__ vb3,
                 float* __restrict__ var_out)
{
    __shared__ __align__(16) short s_a[4*3248];     // conv1_v 20x20 halo, 4 ch-slices
    __shared__ __align__(16) short s_f[18*18*40];   // conv2_v out 18x18, 40-short stride
    __shared__ float s_w3[288];
    const int tid = threadIdx.x;
    const int lane = tid & 63, wid = tid >> 6;
    const int m = lane & 15, quad = lane >> 4, k0 = quad*8;
    const int n  = blockIdx.z;
    const int x0 = blockIdx.x * 16;
    const int y0 = blockIdx.y * 16;

    const short* inp = (const short*)in + (size_t)n*PLANE*32;

    // stage 20x20 halo of conv1_v output, zero-padded outside image
    for (int c = tid; c < 1600; c += 256) {
        int q = c & 3, px = c >> 2;
        int yy = px / 20, xx = px - yy*20;
        int gy = y0 + yy - 2, gx = x0 + xx - 2;
        short8 v = {0,0,0,0,0,0,0,0};
        if ((unsigned)gy < 256u && (unsigned)gx < 256u)
            v = *(const short8*)(inp + ((size_t)(gy*256 + gx))*32 + q*8);
        *(short8*)(s_a + q*3248 + (yy*20 + xx)*8) = v;
    }
    for (int i = tid; i < 288; i += 256) s_w3[i] = vw3[i];

    const short* wp = (const short*)wpk;
    short8 bw[2][9];
    #pragma unroll
    for (int g = 0; g < 2; g++)
        #pragma unroll
        for (int tap = 0; tap < 9; tap++)
            bw[g][tap] = *(const short8*)(wp + ((tap*32 + g*16 + m)*32 + k0));
    const float b0 = bias[m], b1 = bias[16 + m];
    __syncthreads();

    const short* sa = s_a + quad*3248;
    for (int ly = wid; ly < 18; ly += 4) {
        f32x4 acc0 = { b0, b0, b0, b0 };
        f32x4 acc1 = { b1, b1, b1, b1 };
        #pragma unroll
        for (int ky = 0; ky < 3; ky++)
        #pragma unroll
        for (int kx = 0; kx < 3; kx++) {
            short8 a = *(const short8*)(sa + ((ly+ky)*20 + (m+kx))*8);
            acc0 = __builtin_amdgcn_mfma_f32_16x16x32_bf16(a, bw[0][ky*3+kx], acc0, 0, 0, 0);
            acc1 = __builtin_amdgcn_mfma_f32_16x16x32_bf16(a, bw[1][ky*3+kx], acc1, 0, 0, 0);
        }
        #pragma unroll
        for (int reg = 0; reg < 4; reg++) {
            int lx = quad*4 + reg;
            short* fp = s_f + (ly*18 + lx)*40;
            fp[m]      = f2bf(fmaxf(acc0[reg], 0.f));
            fp[16 + m] = f2bf(fmaxf(acc1[reg], 0.f));
        }
        // extra cols lx=16,17 (A rows 0,1 valid; others clamped garbage, discarded)
        f32x4 e0 = { b0, b0, b0, b0 };
        f32x4 e1 = { b1, b1, b1, b1 };
        #pragma unroll
        for (int ky = 0; ky < 3; ky++)
        #pragma unroll
        for (int kx = 0; kx < 3; kx++) {
            int col = 16 + m + kx; if (col > 19) col = 19;
            short8 a = *(const short8*)(sa + ((ly+ky)*20 + col)*8);
            e0 = __builtin_amdgcn_mfma_f32_16x16x32_bf16(a, bw[0][ky*3+kx], e0, 0, 0, 0);
            e1 = __builtin_amdgcn_mfma_f32_16x16x32_bf16(a, bw[1][ky*3+kx], e1, 0, 0, 0);
        }
        if (quad == 0) {
            #pragma unroll
            for (int reg = 0; reg < 2; reg++) {
                short* fp = s_f + (ly*18 + 16 + reg)*40;
                fp[m]      = f2bf(fmaxf(e0[reg], 0.f));
                fp[16 + m] = f2bf(fmaxf(e1[reg], 0.f));
            }
        }
    }
    __syncthreads();

    // conv3 (32->1), exact conv3x3_last tap/FMA order, inputs from LDS
    const int ty = tid >> 4, tx = tid & 15;
    const int h = y0 + ty, w = x0 + tx;
    float sum = vb3[0];
    #pragma unroll
    for (int ky = 0; ky < 3; ky++) {
        int yy = h + ky - 1;
        if ((unsigned)yy >= 256u) continue;
        #pragma unroll
        for (int kx = 0; kx < 3; kx++) {
            int xx = w + kx - 1;
            if ((unsigned)xx >= 256u) continue;
            const short8* pp = (const short8*)(s_f + ((ty+ky)*18 + (tx+kx))*40);
            int tap = ky*3 + kx;
            #pragma unroll
            for (int c4 = 0; c4 < 4; c4++) {
                short8 v = pp[c4];
                #pragma unroll
                for (int j = 0; j < 8; j++)
                    sum = fmaf(bf2f(v[j]), s_w3[(c4*8+j)*9 + tap], sum);
            }
        }
    }
    var_out[(size_t)n*PLANE + h*256 + w] = sum;
}

// ======== conv1_v (blocks < 4096) + aff2 (blocks >= 4096) in ONE dispatch ========
__global__ __launch_bounds__(256)
void conv1v_aff(const float* __restrict__ guide, const float* __restrict__ ybic,
                const float* __restrict__ vw1, const float* __restrict__ vb1,
                bf16* __restrict__ outv,
                const float* __restrict__ dv, const float* __restrict__ dh,
                const float* __restrict__ llam, const float* __restrict__ lmu,
                unsigned* __restrict__ wvh, float* __restrict__ aff)
{
    __shared__ float s_in[4*324];
    __shared__ float s_w[4*9*32];
    const int b = blockIdx.x;
    if (b < 4096) {
        int n = b >> 8, by = (b >> 4) & 15, bx = b & 15;
        conv1_body<4,3>(guide, ybic, vw1, vb1, outv, s_in, s_w,
                        n, by*16, bx*16, threadIdx.x);
        return;
    }
    // aff2 body (exact r8 aff2_kernel math)
    int bid = b - 4096;
    int n = bid >> 8, h = bid & 255, w = threadIdx.x;
    float mu = expf(lmu[0]), lam = expf(llam[0]);
    int rb = (n*256 + h)*256 + w;
    float wvv = (h < 255) ? expf(-mu * dv[rb]) : 0.f;
    float whv = (w < 255) ? expf(-mu * dh[rb]) : 0.f;
    unsigned pv = (unsigned)(unsigned short)f2bf(wvv);
    unsigned ph = (unsigned)(unsigned short)f2bf(whv);
    wvh[rb] = pv | (ph << 16);
    float w_up = (h > 0) ? expf(-mu * dv[rb - 256]) : 0.f;
    float w_lf = (w > 0) ? expf(-mu * dh[rb - 1])   : 0.f;
    float ctr  = w_up + wvv + w_lf + whv + lam;
    float* a = aff + ((size_t)n*5)*PLANE + h*256 + w;
    a[0]        = w_up;
    a[PLANE]    = wvv;
    a[2*PLANE]  = w_lf;
    a[3*PLANE]  = whv;
    a[4*PLANE]  = ctr;
}

// ============ persistent CG: 512 workers, 2-level reduce, PACKED 16B sync lines ============
__global__ __launch_bounds__(256, 2)
void cg_persist(const unsigned* __restrict__ wvh, const float* __restrict__ mask,
                const float* __restrict__ src, const float* __restrict__ ybic,
                const float* __restrict__ llam, float* __restrict__ xout,
                float* __restrict__ ebuf0, float* __restrict__ ebuf1,
                float* __restrict__ part4, float* __restrict__ res4)
{
    __shared__ float s_pn[66][34];
    __shared__ float s_part[256], s_bs[32];
    __shared__ float s_w3[12];
    __shared__ __align__(16) float s_g[16];

    const int tid = threadIdx.x;
    const int wb = blockIdx.x;
    const int n = wb >> 5, t = wb & 31;
    const int tyo = (t >> 3) * 64, txo = (t & 7) * 32;
    const int tx = tid & 31, tyb = tid >> 5;
    const int w = txo + tx;
    const float lam = expf(llam[0]);
    const bool is_leader = ((wb & 127) == 0);

    const unsigned* wn = wvh + (size_t)n*PLANE;
    const float* ybn = ybic + (size_t)n*PLANE;

    int idx[8];
    unsigned wc[8], wu[8], wl[8];
    float c1[8], rhs[8];
    #pragma unroll
    for (int i = 0; i < 8; i++) {
        int hhi = tyo + tyb + 8*i;
        idx[i] = hhi*256 + w;
        wc[i] = wn[idx[i]];
        wu[i] = (hhi > 0) ? wn[idx[i]-256] : 0u;
        wl[i] = (w > 0)   ? wn[idx[i]-1]   : 0u;
        int bi = n*1024 + (hhi>>3)*32 + (w>>3);
        float mv = mask[bi];
        c1[i]  = lam*mv*(1.f/4096.f);
        rhs[i] = lam*mv*src[bi]*(1.f/64.f);
    }

    const bool hthr = (tid < 192);
    int hy = 0, hx = 0; bool hin = false; int nb = 0, eoff = 0;
    if (hthr) {
        if      (tid < 32)  { hy = tyo - 1;         hx = txo + tid;
                              nb = wb - 8; eoff = 32 + tid; }
        else if (tid < 64)  { hy = tyo + 64;        hx = txo + (tid-32);
                              nb = wb + 8; eoff = tid - 32; }
        else if (tid < 128) { hy = tyo + (tid-64);  hx = txo - 1;
                              nb = wb - 1; eoff = 128 + (tid-64); }
        else                { hy = tyo + (tid-128); hx = txo + 32;
                              nb = wb + 1; eoff = 64 + (tid-128); }
        hin = (hy >= 0 && hy < 256 && hx >= 0 && hx < 256);
    }
    const int hsy = hy - tyo + 1, hsx = hx - txo + 1;

    #define POOL_BLOCK() do { \
        __syncthreads(); \
        { int segrow_ = tid >> 2, segcol_ = tid & 3; \
          const float* rw_ = &s_pn[1 + segrow_][1 + segcol_*8]; \
          s_part[tid] = rw_[0]+rw_[1]+rw_[2]+rw_[3]+rw_[4]+rw_[5]+rw_[6]+rw_[7]; } \
        __syncthreads(); \
        if (tid < 32) { int brow_ = tid >> 2, bcol_ = tid & 3; float s_ = 0.f; \
          _Pragma("unroll") \
          for (int rr_ = 0; rr_ < 8; rr_++) s_ += s_part[(brow_*8 + rr_)*4 + bcol_]; \
          s_bs[tid] = s_; } \
        __syncthreads(); \
    } while (0)

    #define PUBLISH_E(arr, ebase) do { \
        float* eb_ = (ebase) + (size_t)wb*192; \
        if (tyb == 0) stg_ag(eb_ + tx, arr[0]); \
        if (tyb == 7) stg_ag(eb_ + 32 + tx, arr[7]); \
        if (tx == 0) { _Pragma("unroll") \
            for (int i_ = 0; i_ < 8; i_++) stg_ag(eb_ + 64 + tyb + 8*i_, arr[i_]); } \
        if (tx == 31){ _Pragma("unroll") \
            for (int i_ = 0; i_ < 8; i_++) stg_ag(eb_ + 128 + tyb + 8*i_, arr[i_]); } \
    } while (0)

    auto matvec = [&](int i) -> float {
        int yy = 1 + tyb + 8*i, xx = 1 + tx;
        float wvd = bf2f((short)(wc[i] & 0xffff));
        float whr = bf2f((short)(wc[i] >> 16));
        float wvu = bf2f((short)(wu[i] & 0xffff));
        float whl = bf2f((short)(wl[i] >> 16));
        float s = wvu*s_pn[yy-1][xx] + wvd*s_pn[yy+1][xx]
                + whl*s_pn[yy][xx-1] + whr*s_pn[yy][xx+1];
        float deg = wvu+wvd+whl+whr;
        return deg*s_pn[yy][xx] - s + c1[i]*s_bs[i*4 + (tx>>3)];
    };

    auto publish_red = [&](unsigned seq, float va, float vb, float vc){
        #pragma unroll
        for (int o = 32; o > 0; o >>= 1) {
            va += __shfl_down(va, o, 64);
            vb += __shfl_down(vb, o, 64);
            vc += __shfl_down(vc, o, 64);
        }
        asm volatile("s_waitcnt vmcnt(0)" ::: "memory");  // per-wave edge-store drain
        __syncthreads();
        if ((tid & 63) == 0) { int wv = tid >> 6; s_w3[wv*3]=va; s_w3[wv*3+1]=vb; s_w3[wv*3+2]=vc; }
        __syncthreads();
        if (tid == 0) {
            f32x4 pk;
            pk[0] = s_w3[0]+s_w3[3]+s_w3[6]+s_w3[9];
            pk[1] = s_w3[1]+s_w3[4]+s_w3[7]+s_w3[10];
            pk[2] = s_w3[2]+s_w3[5]+s_w3[8]+s_w3[11];
            pk[3] = __uint_as_float(seq);
            stg4_ag(part4 + (size_t)((seq & 1)*512 + wb)*4, pk);
        }
    };

    float o0, o1, o2;
    auto allred = [&](unsigned seq){
        float* resp = res4 + (size_t)(seq & 1)*64;
        if (is_leader && tid < 64) {
            const float* pl = part4 + (size_t)(seq & 1)*2048;
            const float* p0 = pl + (size_t)(wb + 2*tid)*4;
            f32x4 a0 = ldg4_ag(p0);
            while (__float_as_uint(a0[3]) < seq) { __builtin_amdgcn_s_sleep(1); a0 = ldg4_ag(p0); }
            f32x4 a1 = ldg4_ag(p0 + 4);
            while (__float_as_uint(a1[3]) < seq) { __builtin_amdgcn_s_sleep(1); a1 = ldg4_ag(p0 + 4); }
            float pa = a0[0] + a1[0];
            float pb = a0[1] + a1[1];
            float pc = a0[2] + a1[2];
            #pragma unroll
            for (int o = 32; o > 0; o >>= 1) {
                pa += __shfl_down(pa, o, 64);
                pb += __shfl_down(pb, o, 64);
                pc += __shfl_down(pc, o, 64);
            }
            if (tid == 0) {
                f32x4 rk; rk[0] = pa; rk[1] = pb; rk[2] = pc; rk[3] = __uint_as_float(seq);
                stg4_ag(resp + (wb >> 7)*16, rk);
            }
        }
        if (tid < 4) {
            const float* rl = resp + tid*16;
            f32x4 g = ldg4_ag(rl);
            while (__float_as_uint(g[3]) < seq) { __builtin_amdgcn_s_sleep(2); g = ldg4_ag(rl); }
            *(f32x4*)&s_g[tid*4] = g;
        }
        __syncthreads();
        o0 = ((s_g[0]+s_g[4])+s_g[8])+s_g[12];
        o1 = ((s_g[1]+s_g[5])+s_g[9])+s_g[13];
        o2 = ((s_g[2]+s_g[6])+s_g[10])+s_g[14];
    };

    float xv[8], rv[8], pv[8], apv[8];
    float rh = 0.f, phh = 0.f;

    // ---------- phase 1 (seq=1) ----------
    #pragma unroll
    for (int i = 0; i < 8; i++) {
        xv[i] = ybn[idx[i]];
        s_pn[1 + tyb + 8*i][1 + tx] = xv[i];
    }
    if (hthr) s_pn[hsy][hsx] = hin ? ybn[hy*256 + hx] : 0.f;
    POOL_BLOCK();
    float g0t = 0.f;
    #pragma unroll
    for (int i = 0; i < 8; i++) {
        float ax = matvec(i);
        float r0 = rhs[i] - ax;
        rv[i] = r0; pv[i] = r0;
        g0t += r0*r0;
    }
    PUBLISH_E(pv, ebuf1);
    publish_red(1u, 0.f, 0.f, 0.f);   // barrier-only phase
    allred(1u);

    // ---------- phase 2 (seq=2, k=0) ----------
    {
        float hv = 0.f;
        if (hthr && hin) hv = ldg_ag(ebuf1 + (size_t)nb*192 + eoff);
        if (hthr) { rh = hv; phh = hv; s_pn[hsy][hsx] = phh; }
        #pragma unroll
        for (int i = 0; i < 8; i++) s_pn[1 + tyb + 8*i][1 + tx] = pv[i];
        POOL_BLOCK();
        float pap = 0.f, apap = 0.f;
        #pragma unroll
        for (int i = 0; i < 8; i++) {
            float ap = matvec(i);
            apv[i] = ap;
            pap  += pv[i]*ap;
            apap += ap*ap;
        }
        PUBLISH_E(apv, ebuf0);
        publish_red(2u, g0t, pap, apap);
    }

    // ---------- main loop k=1..99 ----------
    for (int k = 1; k <= 99; k++) {
        float* ebR = ((k+1) & 1) ? ebuf1 : ebuf0;
        float* ebW = ((k+2) & 1) ? ebuf1 : ebuf0;

        allred((unsigned)(k + 1));
        float alpha = o0 / o1;
        float beta  = (alpha*alpha*o2 - o0) / o0;

        float hv = 0.f;
        if (hthr && hin) hv = ldg_ag(ebR + (size_t)nb*192 + eoff);

        float gsum = 0.f;
        #pragma unroll
        for (int i = 0; i < 8; i++) {
            float rN = fmaf(-alpha, apv[i], rv[i]);
            xv[i] = fmaf(alpha, pv[i], xv[i]);
            float pN = fmaf(beta, pv[i], rN);
            rv[i] = rN; pv[i] = pN;
            gsum += rN*rN;
            s_pn[1 + tyb + 8*i][1 + tx] = pN;
        }
        if (hthr) {
            rh  = fmaf(-alpha, hv, rh);
            phh = fmaf(beta, phh, rh);
            s_pn[hsy][hsx] = phh;
        }
        POOL_BLOCK();
        float pap = 0.f, apap = 0.f;
        #pragma unroll
        for (int i = 0; i < 8; i++) {
            float ap = matvec(i);
            apv[i] = ap;
            pap  += pv[i]*ap;
            apap += ap*ap;
        }
        PUBLISH_E(apv, ebW);
        publish_red((unsigned)(k + 2), gsum, pap, apap);
    }

    // ---------- tail ----------
    allred(101u);
    float alphaT = o0 / o1;
    float* xn = xout + (size_t)n*PLANE;
    #pragma unroll
    for (int i = 0; i < 8; i++) xn[idx[i]] = fmaf(alphaT, pv[i], xv[i]);

    #undef POOL_BLOCK
    #undef PUBLISH_E
}

// ---------------- host ----------------
extern "C" void kernel_launch(void* const* d_in, const int* in_sizes, int n_in,
                              void* d_out, int out_size, void* d_ws, size_t ws_size,
                              hipStream_t stream)
{
    (void)in_sizes; (void)n_in; (void)out_size; (void)ws_size;
    const float* guide = (const float*)d_in[0];
    const float* source= (const float*)d_in[1];
    const float* mask  = (const float*)d_in[2];
    const float* ybic  = (const float*)d_in[3];
    const float* gw1 = (const float*)d_in[4];  const float* gb1 = (const float*)d_in[5];
    const float* gw2 = (const float*)d_in[6];  const float* gb2 = (const float*)d_in[7];
    const float* sw1 = (const float*)d_in[8];  const float* sb1 = (const float*)d_in[9];
    const float* sw2 = (const float*)d_in[10]; const float* sb2 = (const float*)d_in[11];
    const float* vw1 = (const float*)d_in[12]; const float* vb1 = (const float*)d_in[13];
    const float* vw2 = (const float*)d_in[14]; const float* vb2 = (const float*)d_in[15];
    const float* vw3 = (const float*)d_in[16]; const float* vb3 = (const float*)d_in[17];
    const float* llam = (const float*)d_in[18];
    const float* lmu  = (const float*)d_in[19];

    float* out     = (float*)d_out;
    float* x_out   = out;                 // y_pred (16,1,256,256)
    float* var_out = out + 1048576;       // var
    float* aff_out = out + 2097152;       // aff (16,5,256,256)

    // ---- workspace layout ----
    char* ws = (char*)d_ws;
    float*    res4  = (float*)ws;                       // 2 parity x 4 x 16 floats [0,512)
    float*    part4 = (float*)(ws + 4096);              // 2 parity x 512 x 16B -> [4096, 20480)
    bf16*     wpk1  = (bf16*)(ws + 24576);              // 18 KiB each
    bf16*     wpk2  = (bf16*)(ws + 43008);
    bf16*     wpk3  = (bf16*)(ws + 61440);              // ends at 79872
    unsigned* wvh   = (unsigned*)(ws + 131072);         // [128 KiB, 128 KiB + 4 MiB)
    char*     A     = ws + 131072 + (size_t)NB*PLANE*4; // shared region (136 MiB)
    // conv-phase mapping of A:
    bf16*  tmpA = (bf16*)(A);                                  // 64 MiB (conv1 g / conv1 v)
    bf16*  tmpB = (bf16*)(A + (size_t)NB*32*PLANE*2);          // 64 MiB (conv1 s)
    float* dv   = (float*)(A + (size_t)NB*32*PLANE*4);         // 4 MiB
    float* dh   = (float*)(A + (size_t)NB*32*PLANE*4 + (size_t)NB*PLANE*4);
    // CG-phase mapping of A (conv temporaries dead by then): compact edge buffers
    float* ebuf0 = (float*)A;                                  // 512*192 floats
    float* ebuf1 = (float*)(A + (size_t)512*192*4);

    // zero res4 + part4 seq fields; zero dv/dh (atomic accumulation base)
    hipMemsetAsync(ws, 0, 20480, stream);
    hipMemsetAsync(dv, 0, (size_t)2*NB*PLANE*4, stream);

    // repack the three 32->32 conv weights into MFMA fragment layout
    wrepack3<<<108,256,0,stream>>>(gw2, sw2, vw2, wpk1, wpk2, wpk3);

    // conv1 for g and s branches concurrently (z 0..31)
    conv1_gs<<<dim3(16,16,2*NB),256,0,stream>>>(guide, ybic, gw1, gb1, sw1, sb1,
                                                tmpA, tmpB);
    // conv2+dvdh for both branches concurrently (atomicAdd into zeroed dv/dh)
    conv2gs_dvdh<<<dim3(16,16,2*NB),256,0,stream>>>(tmpA, tmpB, wpk1, gb2, wpk2, sb2,
                                                    dv, dh);
    // conv1_v (tmpA reuse) and aff2 concurrently in one dispatch
    conv1v_aff<<<8192,256,0,stream>>>(guide, ybic, vw1, vb1, tmpA,
                                      dv, dh, llam, lmu, wvh, aff_out);
    // fused v-tail: conv2_v(RELU) + conv3 -> var (no tmpB round-trip)
    conv2v_last<<<dim3(16,16,NB),256,0,stream>>>(tmpA, wpk3, vb2, vw3, vb3, var_out);

    // CG: ONE persistent dispatch — 512 workers, packed-line 2-level barrier
    cg_persist<<<512,256,0,stream>>>(wvh, mask, source, ybic, llam, x_out,
                                     ebuf0, ebuf1, part4, res4);
}